// Round 3
// baseline (1407.838 us; speedup 1.0000x reference)
//
#include <hip/hip_runtime.h>
#include <stdint.h>

// ---------- helpers ----------
typedef __attribute__((ext_vector_type(8))) short bf16x8;
typedef __attribute__((ext_vector_type(4))) float f32x4;

__device__ __forceinline__ float b2f(unsigned short s) {
    unsigned int u = ((unsigned int)s) << 16;
    return __builtin_bit_cast(float, u);
}
__device__ __forceinline__ unsigned short f2b(float f) {
    unsigned int u = __builtin_bit_cast(unsigned int, f);
    u += 0x7FFFu + ((u >> 16) & 1u);   // RNE
    return (unsigned short)(u >> 16);
}

#define EPS_ATTN 1e-8f
#define LN_EPS 1e-5f
#define SCALE 0.0625f  // 256^-0.5

// ---------- prep: W3 in MFMA B-fragment order ----------
__global__ __launch_bounds__(256) void k_prep(const float* __restrict__ wk,
                                              const float* __restrict__ wv,
                                              unsigned short* __restrict__ W3) {
    int g = blockIdx.x * 256 + threadIdx.x;   // 131072
    int j = g & 7;
    int f = (g >> 3) & 1023;
    int stage = g >> 13;
    int p = f & 15, qq = (f >> 4) & 3, ntl = f >> 6;
    int kc = stage >> 1, half_ = stage & 1;
    int k = kc * 32 + qq * 8 + j;
    int n = half_ * 256 + ntl * 16 + p;
    float v = (n < 256) ? wk[k * 256 + n] : wv[k * 256 + (n - 256)];
    W3[g] = f2b(v);
}

// ---------- slot init ----------
__global__ __launch_bounds__(256) void k_init(const float* __restrict__ sm,
                                              const float* __restrict__ slv,
                                              const float* __restrict__ noise,
                                              float* __restrict__ slots) {
    int idx = blockIdx.x * 256 + threadIdx.x; // 131072
    int d = idx & 255;
    slots[idx] = sm[d] + expf(slv[d]) * noise[idx];
}

// ---------- fused LN(inputs) + K/V projection ----------
// B fragments loaded DIRECTLY global->VGPR (W3 L2-resident); barrier-free MFMA loop.
// Epilogue: TWO passes through ONE 32KB restage buffer (K then V) -> LDS 34.8KB
// -> 4 blocks/CU (was 2). K out [bh][n][32]; V out transposed [bh][d][4096].
__global__ __launch_bounds__(256, 4) void k_kv(
    const float* __restrict__ x, const float* __restrict__ lnw, const float* __restrict__ lnb,
    const unsigned short* __restrict__ W3, const float* __restrict__ bk, const float* __restrict__ bv,
    unsigned short* __restrict__ Kb, unsigned short* __restrict__ Vb) {
    __shared__ __align__(16) unsigned short sh[16384];  // 32KB: A frags, then repK, then repV
    __shared__ __align__(16) float bL[512];             // 2KB biases
    unsigned short* As = sh;
    int t = threadIdx.x;
    int w = t >> 6, lane = t & 63;
    int p = lane & 15, q = lane >> 4;

    if (t < 128) {
        float4 bb = (t < 64) ? ((const float4*)bk)[t] : ((const float4*)bv)[t - 64];
        *(float4*)&bL[t * 4] = bb;
    }

    // ---- LN(x) -> As (bf16, xor-swizzled A fragments) ----
    float4 lw  = ((const float4*)lnw)[lane];
    float4 lbv = ((const float4*)lnb)[lane];
    float4 xv[16];
    const float* xbase = x + ((size_t)blockIdx.x * 64 + w * 16) * 256;
    #pragma unroll
    for (int i = 0; i < 16; ++i) xv[i] = ((const float4*)(xbase + i * 256))[lane];
    int kcw = lane >> 3, qw = (lane >> 1) & 3, j0 = (lane & 1) * 4;
    #pragma unroll
    for (int i = 0; i < 16; ++i) {
        float4 v = xv[i];
        float s0 = v.x + v.y + v.z + v.w;
        float s1 = v.x * v.x + v.y * v.y + v.z * v.z + v.w * v.w;
        #pragma unroll
        for (int o = 1; o < 64; o <<= 1) { s0 += __shfl_xor(s0, o); s1 += __shfl_xor(s1, o); }
        float mean = s0 * (1.0f / 256.0f);
        float var  = s1 * (1.0f / 256.0f) - mean * mean;
        float rstd = rsqrtf(var + LN_EPS);
        ushort4 pk;
        pk.x = f2b((v.x - mean) * rstd * lw.x + lbv.x);
        pk.y = f2b((v.y - mean) * rstd * lw.y + lbv.y);
        pk.z = f2b((v.z - mean) * rstd * lw.z + lbv.z);
        pk.w = f2b((v.w - mean) * rstd * lw.w + lbv.w);
        int pos = (qw * 16 + i) ^ kcw;
        *(ushort4*)&As[((w * 8 + kcw) * 64 + pos) * 8 + j0] = pk;
    }
    __syncthreads();

    // ---- barrier-free MFMA main loop ----
    // wave strip: cols [w*128, w*128+128) => half = w>>1, ntl in [(w&1)*8, +8)
    f32x4 acc[4][8];
    f32x4 zero = {0.f, 0.f, 0.f, 0.f};
    #pragma unroll
    for (int rt = 0; rt < 4; ++rt)
        #pragma unroll
        for (int ct = 0; ct < 8; ++ct) acc[rt][ct] = zero;

    const unsigned short* Wb = W3 + (size_t)(w >> 1) * 8192 + (size_t)((w & 1) * 8) * 512 + lane * 8;
    #pragma unroll 2
    for (int kc = 0; kc < 8; ++kc) {
        bf16x8 af[4];
        #pragma unroll
        for (int rt = 0; rt < 4; ++rt)
            af[rt] = *(const bf16x8*)&As[((rt * 8 + kc) * 64 + ((q * 16 + p) ^ kc)) * 8];
        #pragma unroll
        for (int ct = 0; ct < 8; ++ct) {
            bf16x8 bf = *(const bf16x8*)(Wb + (size_t)kc * 16384 + ct * 512);
            #pragma unroll
            for (int rt = 0; rt < 4; ++rt)
                acc[rt][ct] = __builtin_amdgcn_mfma_f32_16x16x32_bf16(af[rt], bf, acc[rt][ct], 0, 0, 0);
        }
    }
    __syncthreads();   // As reads done; safe to overwrite

    unsigned short* rep = As;
    int b_  = blockIdx.x >> 6;
    int n0g = (blockIdx.x & 63) * 64;

    // ---- pass 1: K (cols 0..255, owned by waves 0,1) ----
    if (w < 2) {
        #pragma unroll
        for (int ct = 0; ct < 8; ++ct) {
            int col = w * 128 + ct * 16 + p;
            float bias = bL[col];
            int hl = col >> 5, dh = col & 31;
            #pragma unroll
            for (int rt = 0; rt < 4; ++rt) {
                #pragma unroll
                for (int r = 0; r < 4; ++r) {
                    int nl = rt * 16 + q * 4 + r;
                    rep[(hl * 64 + nl) * 32 + dh] = f2b(acc[rt][ct][r] + bias);
                }
            }
        }
    }
    __syncthreads();
    #pragma unroll
    for (int i = 0; i < 8; ++i) {
        uint4 vd = *(const uint4*)&rep[(i * 256 + t) * 8];
        *(uint4*)(Kb + (((size_t)b_ * 8 + i) * 4096 + n0g) * 32 + t * 8) = vd;
    }
    __syncthreads();

    // ---- pass 2: V (cols 256..511, owned by waves 2,3), even-XOR chunk swizzle ----
    if (w >= 2) {
        #pragma unroll
        for (int ct = 0; ct < 8; ++ct) {
            int vrow = (w - 2) * 128 + ct * 16 + p;
            float bias = bL[256 + vrow];
            #pragma unroll
            for (int rt = 0; rt < 4; ++rt) {
                int chunk = (rt * 4 + q) ^ (p & 14);
                ushort4 pk;
                pk.x = f2b(acc[rt][ct][0] + bias);
                pk.y = f2b(acc[rt][ct][1] + bias);
                pk.z = f2b(acc[rt][ct][2] + bias);
                pk.w = f2b(acc[rt][ct][3] + bias);
                *(ushort4*)&rep[vrow * 64 + chunk * 4] = pk;
            }
        }
    }
    __syncthreads();
    #pragma unroll
    for (int i = 0; i < 8; ++i) {
        int vrow = i * 32 + (t >> 3);
        int c16 = t & 7;
        uint4 vd = *(const uint4*)&rep[vrow * 64 + ((2 * c16) ^ (vrow & 14)) * 4];
        *(uint4*)(Vb + ((size_t)(b_ * 8 + (vrow >> 5)) * 32 + (vrow & 31)) * 4096 + n0g + c16 * 8) = vd;
    }
}

// ---------- q projection ----------
__global__ __launch_bounds__(256) void k_q(
    const float* __restrict__ slots, const float* __restrict__ lnw, const float* __restrict__ lnb,
    const float* __restrict__ wq, const float* __restrict__ bq, float* __restrict__ qg) {
    __shared__ float sln[256];
    __shared__ float red[8];
    int t = threadIdx.x;
    int row = blockIdx.x;
    float v = slots[(size_t)row * 256 + t];
    float s0 = v, s1 = v * v;
    #pragma unroll
    for (int off = 1; off < 64; off <<= 1) { s0 += __shfl_xor(s0, off); s1 += __shfl_xor(s1, off); }
    if ((t & 63) == 0) { red[t >> 6] = s0; red[4 + (t >> 6)] = s1; }
    __syncthreads();
    float ts0 = red[0] + red[1] + red[2] + red[3];
    float ts1 = red[4] + red[5] + red[6] + red[7];
    float mean = ts0 * (1.f / 256.f);
    float var  = ts1 * (1.f / 256.f) - mean * mean;
    float rstd = rsqrtf(var + LN_EPS);
    sln[t] = (v - mean) * rstd * lnw[t] + lnb[t];
    __syncthreads();
    float acc = bq[t];
    #pragma unroll 4
    for (int k = 0; k < 256; ++k) acc += sln[k] * wq[k * 256 + t];
    int b = row >> 3, sl = row & 7;
    qg[(size_t)b * 2048 + (t >> 5) * 256 + sl * 32 + (t & 31)] = acc;
}

// ---------- attention sweep: MFMA QK^T (swapped) + MFMA PV ----------
// grid 2048 = bh(512) x chunk(4); 256 threads (4 waves); wave handles 256 n (8 prs).
// Cross-block partials: upd_part[bh][4][256], rowsum_part[bh][4][8] (summed in k_gA).
__global__ __launch_bounds__(256) void k_attn(
    const unsigned short* __restrict__ Kg, const unsigned short* __restrict__ VTg,
    const float* __restrict__ qg, float* __restrict__ upd_part, float* __restrict__ rowsum_part,
    float* __restrict__ attn_out, int last) {
    __shared__ float supd[4][256];
    __shared__ float srs[4][8];
    int t = threadIdx.x;
    int w = t >> 6, lane = t & 63;
    int c = lane & 15;     // QK-C col = slot s ; PV A row = d ; PV-C col = s
    int g = lane >> 4;     // lane group

    int bh = blockIdx.x >> 2;
    int chunk = blockIdx.x & 3;
    const unsigned short* Kbh = Kg  + (size_t)bh * 4096 * 32;
    const unsigned short* Vbh = VTg + (size_t)bh * 32 * 4096;

    // Q B-fragment: lane holds Q[s=c][d=g*8+j], bf16 hi+lo split; zero for s>=8.
    bf16x8 qhi = {0,0,0,0,0,0,0,0};
    bf16x8 qlo = {0,0,0,0,0,0,0,0};
    if (c < 8) {
        const float* qp = qg + (size_t)bh * 256 + c * 32 + g * 8;
        #pragma unroll
        for (int j = 0; j < 8; ++j) {
            float qv = qp[j];
            unsigned short hb = f2b(qv);
            qhi[j] = (short)hb;
            qlo[j] = (short)f2b(qv - b2f(hb));
        }
    }

    f32x4 zero = {0.f, 0.f, 0.f, 0.f};
    f32x4 accL = zero, accH = zero;
    float rs = 0.f;
    int nb0 = chunk * 1024 + w * 256;

    #pragma unroll 2
    for (int pr = 0; pr < 8; ++pr) {
        int base = nb0 + pr * 32;
        bf16x8 k0 = *(const bf16x8*)(Kbh + (size_t)(base + c) * 32 + g * 8);
        bf16x8 k1 = *(const bf16x8*)(Kbh + (size_t)(base + 16 + c) * 32 + g * 8);
        const unsigned short* vlo = Vbh + (size_t)c * 4096 + base + g * 4;
        const unsigned short* vhi = Vbh + (size_t)(c + 16) * 4096 + base + g * 4;
        union { ushort4 h[2]; bf16x8 v; } V0, V1;
        V0.h[0] = *(const ushort4*)vlo;
        V0.h[1] = *(const ushort4*)(vlo + 16);
        V1.h[0] = *(const ushort4*)vhi;
        V1.h[1] = *(const ushort4*)(vhi + 16);

        f32x4 s0 = __builtin_amdgcn_mfma_f32_16x16x32_bf16(k0, qhi, zero, 0, 0, 0);
        s0 = __builtin_amdgcn_mfma_f32_16x16x32_bf16(k0, qlo, s0, 0, 0, 0);
        f32x4 s1 = __builtin_amdgcn_mfma_f32_16x16x32_bf16(k1, qhi, zero, 0, 0, 0);
        s1 = __builtin_amdgcn_mfma_f32_16x16x32_bf16(k1, qlo, s1, 0, 0, 0);

        float d0[4], d1[4];
        #pragma unroll
        for (int r = 0; r < 4; ++r) { d0[r] = s0[r] * SCALE; d1[r] = s1[r] * SCALE; }
        float m = fmaxf(fmaxf(fmaxf(d0[0], d0[1]), fmaxf(d0[2], d0[3])),
                        fmaxf(fmaxf(d1[0], d1[1]), fmaxf(d1[2], d1[3])));
        m = fmaxf(m, __shfl_xor(m, 1));
        m = fmaxf(m, __shfl_xor(m, 2));
        m = fmaxf(m, __shfl_xor(m, 4));
        m = fmaxf(m, __shfl_xor(m, 8));
        float a0[4], a1[4];
        #pragma unroll
        for (int r = 0; r < 4; ++r) {
            float e0 = __expf(d0[r] - m);
            float e1 = __expf(d1[r] - m);
            float t0 = e0;
            t0 += __shfl_xor(t0, 1); t0 += __shfl_xor(t0, 2); t0 += __shfl_xor(t0, 4);
            float t1 = e1;
            t1 += __shfl_xor(t1, 1); t1 += __shfl_xor(t1, 2); t1 += __shfl_xor(t1, 4);
            a0[r] = e0 * (1.0f / t0) + EPS_ATTN;
            a1[r] = e1 * (1.0f / t1) + EPS_ATTN;
            rs += a0[r] + a1[r];
        }
        if (last && c < 8) {
            float4 st0 = {a0[0], a0[1], a0[2], a0[3]};
            float4 st1 = {a1[0], a1[1], a1[2], a1[3]};
            float* ap = attn_out + ((size_t)bh * 8 + c) * 4096 + base + g * 4;
            *(float4*)ap = st0;
            *(float4*)(ap + 16) = st1;
        }
        bf16x8 pah, pal;
        float af[8] = {a0[0], a0[1], a0[2], a0[3], a1[0], a1[1], a1[2], a1[3]};
        #pragma unroll
        for (int j = 0; j < 8; ++j) {
            unsigned short hb = f2b(af[j]);
            pah[j] = (short)hb;
            pal[j] = (short)f2b(af[j] - b2f(hb));
        }
        accL = __builtin_amdgcn_mfma_f32_16x16x32_bf16(V0.v, pah, accL, 0, 0, 0);
        accL = __builtin_amdgcn_mfma_f32_16x16x32_bf16(V0.v, pal, accL, 0, 0, 0);
        accH = __builtin_amdgcn_mfma_f32_16x16x32_bf16(V1.v, pah, accH, 0, 0, 0);
        accH = __builtin_amdgcn_mfma_f32_16x16x32_bf16(V1.v, pal, accH, 0, 0, 0);
    }

    rs += __shfl_xor(rs, 16);
    rs += __shfl_xor(rs, 32);
    if (lane < 8) srs[w][lane] = rs;
    if (c < 8) {
        float* up = &supd[w][c * 32 + g * 4];
        up[0]  = accL[0]; up[1]  = accL[1]; up[2]  = accL[2]; up[3]  = accL[3];
        up[16] = accH[0]; up[17] = accH[1]; up[18] = accH[2]; up[19] = accH[3];
    }
    __syncthreads();
    {
        float v = supd[0][t] + supd[1][t] + supd[2][t] + supd[3][t];
        upd_part[((size_t)bh * 4 + chunk) * 256 + t] = v;
    }
    if (t < 8) {
        float v = srs[0][t] + srs[1][t] + srs[2][t] + srs[3][t];
        rowsum_part[((size_t)bh * 4 + chunk) * 8 + t] = v;
    }
}

// ========== slot-update stage kernels (col-split, LDS row-broadcast) ==========
// Stage A: O = U @ wo + bo; sums the 4 attn partials, emits rowsum_tot (cc==0).
__global__ __launch_bounds__(256) void k_gA(
    const float* __restrict__ upd_part, const float* __restrict__ rowsum_part,
    const float* __restrict__ wo, const float* __restrict__ bo,
    float* __restrict__ O, float* __restrict__ rowsum_tot) {
    __shared__ float Ul[8][256];
    __shared__ float Pp[4][8][64];
    int t = threadIdx.x;
    int b = blockIdx.x >> 2, cc = blockIdx.x & 3;
    int colbase = cc * 64;
    {
        int r = t >> 5, d0 = (t & 31) * 8;
        int h = (t & 31) >> 2;      // d0 >> 5
        float rsum = 0.f;
        #pragma unroll
        for (int ch = 0; ch < 4; ++ch)
            rsum += rowsum_part[((size_t)(b * 8 + h) * 4 + ch) * 8 + r];
        float inv = 1.0f / fmaxf(rsum, 1e-12f);
        float u[8] = {0.f,0.f,0.f,0.f,0.f,0.f,0.f,0.f};
        #pragma unroll
        for (int ch = 0; ch < 4; ++ch) {
            const float* up = upd_part + ((size_t)(b * 8 + h) * 4 + ch) * 256 + r * 32 + (d0 & 31);
            float4 u0 = *(const float4*)up;
            float4 u1 = *(const float4*)(up + 4);
            u[0] += u0.x; u[1] += u0.y; u[2] += u0.z; u[3] += u0.w;
            u[4] += u1.x; u[5] += u1.y; u[6] += u1.z; u[7] += u1.w;
        }
        #pragma unroll
        for (int i = 0; i < 8; ++i) Ul[r][d0 + i] = u[i] * inv;
        if (cc == 0 && (t & 3) == 0) rowsum_tot[(b * 8 + h) * 8 + r] = rsum;
    }
    __syncthreads();
    int c = t & 63, kq = t >> 6;
    float acc[8] = {0.f,0.f,0.f,0.f,0.f,0.f,0.f,0.f};
    const float* wp = wo + (size_t)(kq * 64) * 256 + colbase + c;
    #pragma unroll 16
    for (int k = 0; k < 64; ++k) {
        float wv_ = wp[(size_t)k * 256];
        int kk = kq * 64 + k;
        #pragma unroll
        for (int r = 0; r < 8; ++r) acc[r] += Ul[r][kk] * wv_;
    }
    #pragma unroll
    for (int r = 0; r < 8; ++r) Pp[kq][r][c] = acc[r];
    __syncthreads();
    #pragma unroll
    for (int j = 0; j < 2; ++j) {
        int o = t * 2 + j;
        int r = o >> 6, c2 = o & 63;
        float v = Pp[0][r][c2] + Pp[1][r][c2] + Pp[2][r][c2] + Pp[3][r][c2] + bo[colbase + c2];
        O[(size_t)(b * 8 + r) * 256 + colbase + c2] = v;
    }
}

__global__ __launch_bounds__(256) void k_gB(
    const float* __restrict__ O, const float* __restrict__ slin,
    const float* __restrict__ wih, const float* __restrict__ bih,
    const float* __restrict__ whh, const float* __restrict__ bhh,
    float* __restrict__ gcomb, float* __restrict__ xn, float* __restrict__ hn) {
    __shared__ float Ol[8][256], Hl[8][256];
    __shared__ float Px[2][8][128], Ph[2][8][128];
    int t = threadIdx.x;
    int b = blockIdx.x / 6, cc = blockIdx.x % 6;
    int colbase = cc * 128;
    {
        int r = t >> 5, d0 = (t & 31) * 8;
        const float* op = O + (size_t)(b * 8 + r) * 256 + d0;
        const float* hp = slin + (size_t)(b * 8 + r) * 256 + d0;
        *(float4*)&Ol[r][d0]     = *(const float4*)op;
        *(float4*)&Ol[r][d0 + 4] = *(const float4*)(op + 4);
        *(float4*)&Hl[r][d0]     = *(const float4*)hp;
        *(float4*)&Hl[r][d0 + 4] = *(const float4*)(hp + 4);
    }
    __syncthreads();
    int c = t & 127, kh = t >> 7;
    float ax[8] = {0.f,0.f,0.f,0.f,0.f,0.f,0.f,0.f};
    float ah[8] = {0.f,0.f,0.f,0.f,0.f,0.f,0.f,0.f};
    const float* wxp = wih + (size_t)(kh * 128) * 768 + colbase + c;
    const float* whp = whh + (size_t)(kh * 128) * 768 + colbase + c;
    #pragma unroll 8
    for (int k = 0; k < 128; ++k) {
        float wx = wxp[(size_t)k * 768];
        float wh = whp[(size_t)k * 768];
        int kk = kh * 128 + k;
        #pragma unroll
        for (int r = 0; r < 8; ++r) { ax[r] += Ol[r][kk] * wx; ah[r] += Hl[r][kk] * wh; }
    }
    #pragma unroll
    for (int r = 0; r < 8; ++r) { Px[kh][r][c] = ax[r]; Ph[kh][r][c] = ah[r]; }
    __syncthreads();
    #pragma unroll
    for (int j = 0; j < 4; ++j) {
        int o = t * 4 + j;               // [0,1024)
        int r = o >> 7, c2 = o & 127;
        int cg = colbase + c2;
        int row = b * 8 + r;
        float vx = Px[0][r][c2] + Px[1][r][c2] + bih[cg];
        float vh = Ph[0][r][c2] + Ph[1][r][c2] + bhh[cg];
        if (cg < 512) {
            gcomb[(size_t)row * 512 + cg] = vx + vh;
        } else {
            xn[(size_t)row * 256 + cg - 512] = vx;
            hn[(size_t)row * 256 + cg - 512] = vh;
        }
    }
}

__global__ __launch_bounds__(256) void k_gC(
    const float* __restrict__ gcomb, const float* __restrict__ xn, const float* __restrict__ hn,
    const float* __restrict__ slin, const float* __restrict__ lnfw, const float* __restrict__ lnfb,
    float* __restrict__ slout, float* __restrict__ F) {
    __shared__ float red[8];
    int t = threadIdx.x, row = blockIdx.x;
    float a_r = gcomb[(size_t)row * 512 + t];
    float a_z = gcomb[(size_t)row * 512 + 256 + t];
    float xnv = xn[(size_t)row * 256 + t];
    float hnv = hn[(size_t)row * 256 + t];
    float hp  = slin[(size_t)row * 256 + t];
    float rg = 1.f / (1.f + expf(-a_r));
    float zg = 1.f / (1.f + expf(-a_z));
    float ng = tanhf(xnv + rg * hnv);
    float s1 = (1.f - zg) * ng + zg * hp;
    slout[(size_t)row * 256 + t] = s1;
    float s0 = s1, sq = s1 * s1;
    #pragma unroll
    for (int o = 1; o < 64; o <<= 1) { s0 += __shfl_xor(s0, o); sq += __shfl_xor(sq, o); }
    if ((t & 63) == 0) { red[t >> 6] = s0; red[4 + (t >> 6)] = sq; }
    __syncthreads();
    float ts0 = red[0] + red[1] + red[2] + red[3];
    float ts1 = red[4] + red[5] + red[6] + red[7];
    float mean = ts0 * (1.f / 256.f);
    float var  = ts1 * (1.f / 256.f) - mean * mean;
    float rstd = rsqrtf(var + LN_EPS);
    F[(size_t)row * 256 + t] = (s1 - mean) * rstd * lnfw[t] + lnfb[t];
}

__global__ __launch_bounds__(256) void k_gD(
    const float* __restrict__ F, const float* __restrict__ w1, const float* __restrict__ b1,
    float* __restrict__ H1) {
    __shared__ float Fl[8][256];
    __shared__ float Pp[4][8][64];
    int t = threadIdx.x;
    int b = blockIdx.x >> 2, cc = blockIdx.x & 3;
    int colbase = cc * 64;
    {
        int r = t >> 5, d0 = (t & 31) * 8;
        const float* fp = F + (size_t)(b * 8 + r) * 256 + d0;
        *(float4*)&Fl[r][d0]     = *(const float4*)fp;
        *(float4*)&Fl[r][d0 + 4] = *(const float4*)(fp + 4);
    }
    __syncthreads();
    int c = t & 63, kq = t >> 6;
    float acc[8] = {0.f,0.f,0.f,0.f,0.f,0.f,0.f,0.f};
    const float* wp = w1 + (size_t)(kq * 64) * 256 + colbase + c;
    #pragma unroll 16
    for (int k = 0; k < 64; ++k) {
        float wv_ = wp[(size_t)k * 256];
        int kk = kq * 64 + k;
        #pragma unroll
        for (int r = 0; r < 8; ++r) acc[r] += Fl[r][kk] * wv_;
    }
    #pragma unroll
    for (int r = 0; r < 8; ++r) Pp[kq][r][c] = acc[r];
    __syncthreads();
    #pragma unroll
    for (int j = 0; j < 2; ++j) {
        int o = t * 2 + j;
        int r = o >> 6, c2 = o & 63;
        float v = Pp[0][r][c2] + Pp[1][r][c2] + Pp[2][r][c2] + Pp[3][r][c2] + b1[colbase + c2];
        H1[(size_t)(b * 8 + r) * 256 + colbase + c2] = fmaxf(v, 0.f);
    }
}

__global__ __launch_bounds__(256) void k_gE(
    const float* __restrict__ H1, const float* __restrict__ w2, const float* __restrict__ b2,
    float* __restrict__ slout) {
    __shared__ float Hl[8][256];
    __shared__ float Pp[4][8][64];
    int t = threadIdx.x;
    int b = blockIdx.x >> 2, cc = blockIdx.x & 3;
    int colbase = cc * 64;
    {
        int r = t >> 5, d0 = (t & 31) * 8;
        const float* hp = H1 + (size_t)(b * 8 + r) * 256 + d0;
        *(float4*)&Hl[r][d0]     = *(const float4*)hp;
        *(float4*)&Hl[r][d0 + 4] = *(const float4*)(hp + 4);
    }
    __syncthreads();
    int c = t & 63, kq = t >> 6;
    float acc[8] = {0.f,0.f,0.f,0.f,0.f,0.f,0.f,0.f};
    const float* wp = w2 + (size_t)(kq * 64) * 256 + colbase + c;
    #pragma unroll 16
    for (int k = 0; k < 64; ++k) {
        float wv_ = wp[(size_t)k * 256];
        int kk = kq * 64 + k;
        #pragma unroll
        for (int r = 0; r < 8; ++r) acc[r] += Hl[r][kk] * wv_;
    }
    #pragma unroll
    for (int r = 0; r < 8; ++r) Pp[kq][r][c] = acc[r];
    __syncthreads();
    #pragma unroll
    for (int j = 0; j < 2; ++j) {
        int o = t * 2 + j;
        int r = o >> 6, c2 = o & 63;
        size_t idx = (size_t)(b * 8 + r) * 256 + colbase + c2;
        float v = Pp[0][r][c2] + Pp[1][r][c2] + Pp[2][r][c2] + Pp[3][r][c2] + b2[colbase + c2];
        slout[idx] = slout[idx] + v;
    }
}

// ---------- final attn normalization (float4) ----------
__global__ __launch_bounds__(256) void k_scale(float* __restrict__ attn, const float* __restrict__ rowsum_tot) {
    size_t i4 = ((size_t)blockIdx.x * 256 + threadIdx.x) * 4;
    int row = (int)(i4 >> 12);
    float inv = 1.0f / fmaxf(rowsum_tot[row], 1e-12f);
    float4 v = *(float4*)(attn + i4);
    v.x *= inv; v.y *= inv; v.z *= inv; v.w *= inv;
    *(float4*)(attn + i4) = v;
}

extern "C" void kernel_launch(void* const* d_in, const int* in_sizes, int n_in,
                              void* d_out, int out_size, void* d_ws, size_t ws_size,
                              hipStream_t stream) {
    const float* inputs = (const float*)d_in[0];
    const float* noise  = (const float*)d_in[1];
    const float* sm     = (const float*)d_in[2];
    const float* slv    = (const float*)d_in[3];
    const float* wq     = (const float*)d_in[4];
    const float* bq     = (const float*)d_in[5];
    const float* wk     = (const float*)d_in[6];
    const float* bk     = (const float*)d_in[7];
    const float* wv     = (const float*)d_in[8];
    const float* bv     = (const float*)d_in[9];
    const float* wo     = (const float*)d_in[10];
    const float* bo     = (const float*)d_in[11];
    const float* wih    = (const float*)d_in[12];
    const float* bih    = (const float*)d_in[13];
    const float* whh    = (const float*)d_in[14];
    const float* bhh    = (const float*)d_in[15];
    const float* w1     = (const float*)d_in[16];
    const float* b1     = (const float*)d_in[17];
    const float* w2     = (const float*)d_in[18];
    const float* b2     = (const float*)d_in[19];
    const float* lniw   = (const float*)d_in[20];
    const float* lnib   = (const float*)d_in[21];
    const float* lnsw   = (const float*)d_in[22];
    const float* lnsb   = (const float*)d_in[23];
    const float* lnfw   = (const float*)d_in[24];
    const float* lnfb   = (const float*)d_in[25];

    char* ws = (char*)d_ws;
    unsigned short* Kb = (unsigned short*)ws;                         // 134,217,728  [bh][n][32]
    unsigned short* Vb = (unsigned short*)(ws + 134217728ull);        // 134,217,728  [bh][d][4096] (transposed)
    float* slotsA  = (float*)(ws + 268435456ull);                     // 524,288
    float* slotsB  = (float*)(ws + 268959744ull);                     // 524,288
    float* Rr      = (float*)(ws + 269484032ull);                     // 524,288  (qg / F)
    float* Pr      = (float*)(ws + 270008320ull);                     // 524,288  (W3 / O)
    float* Qr      = (float*)(ws + 270532608ull);                     // 2,097,152 (upd_part / gcomb|xn|hn / H1)
    float* rowsum_part = (float*)(ws + 272629760ull);                 // 65,536
    float* rowsum_tot  = (float*)(ws + 273154048ull);                 // 16,384
    unsigned short* W3 = (unsigned short*)Pr;
    float* O_  = Pr;
    float* upd_part = Qr;                 // 512x4x256 (attn -> gA, dead by gB)
    float* gcomb = Qr;                    // 512x512
    float* xn = Qr + 262144;              // 512x256
    float* hn = Qr + 393216;              // 512x256
    float* H1 = Qr;                       // 512x256 (aliases gcomb, gB->gC dead by gD)
    float* qg = Rr;
    float* F_ = Rr;

    float* out_slots = (float*)d_out;            // [64,8,256]
    float* attn_out  = (float*)d_out + 131072;   // [64,8,8,4096]

    k_prep<<<512, 256, 0, stream>>>(wk, wv, W3);
    k_init<<<512, 256, 0, stream>>>(sm, slv, noise, slotsA);
    k_kv<<<4096, 256, 0, stream>>>(inputs, lniw, lnib, W3, bk, bv, Kb, Vb);
    for (int it = 0; it < 3; ++it) {
        int last = (it == 2);
        float* sl_in  = (it == 0) ? slotsA : ((it == 1) ? slotsB : slotsA);
        float* sl_out = (it == 0) ? slotsB : ((it == 1) ? slotsA : out_slots);
        k_q<<<512, 256, 0, stream>>>(sl_in, lnsw, lnsb, wq, bq, qg);
        k_attn<<<2048, 256, 0, stream>>>(Kb, Vb, qg, upd_part, rowsum_part, attn_out, last);
        k_gA<<<256, 256, 0, stream>>>(upd_part, rowsum_part, wo, bo, O_, rowsum_tot);
        k_gB<<<384, 256, 0, stream>>>(O_, sl_in, wih, bih, whh, bhh, gcomb, xn, hn);
        k_gC<<<512, 256, 0, stream>>>(gcomb, xn, hn, sl_in, lnfw, lnfb, sl_out, F_);
        k_gD<<<256, 256, 0, stream>>>(F_, w1, b1, H1);
        k_gE<<<256, 256, 0, stream>>>(H1, w2, b2, sl_out);
    }
    k_scale<<<16384, 256, 0, stream>>>(attn_out, rowsum_tot);
}

// Round 4
// 1098.453 us; speedup vs baseline: 1.2817x; 1.2817x over previous
//
#include <hip/hip_runtime.h>
#include <stdint.h>

// ---------- helpers ----------
typedef __attribute__((ext_vector_type(8))) short bf16x8;
typedef __attribute__((ext_vector_type(4))) float f32x4;

__device__ __forceinline__ float b2f(unsigned short s) {
    unsigned int u = ((unsigned int)s) << 16;
    return __builtin_bit_cast(float, u);
}
__device__ __forceinline__ unsigned short f2b(float f) {
    unsigned int u = __builtin_bit_cast(unsigned int, f);
    u += 0x7FFFu + ((u >> 16) & 1u);   // RNE
    return (unsigned short)(u >> 16);
}

#define EPS_ATTN 1e-8f
#define LN_EPS 1e-5f
#define SCALE 0.0625f  // 256^-0.5

// ---------- prep: W3 in MFMA B-fragment order ----------
__global__ __launch_bounds__(256) void k_prep(const float* __restrict__ wk,
                                              const float* __restrict__ wv,
                                              unsigned short* __restrict__ W3) {
    int g = blockIdx.x * 256 + threadIdx.x;   // 131072
    int j = g & 7;
    int f = (g >> 3) & 1023;
    int stage = g >> 13;
    int p = f & 15, qq = (f >> 4) & 3, ntl = f >> 6;
    int kc = stage >> 1, half_ = stage & 1;
    int k = kc * 32 + qq * 8 + j;
    int n = half_ * 256 + ntl * 16 + p;
    float v = (n < 256) ? wk[k * 256 + n] : wv[k * 256 + (n - 256)];
    W3[g] = f2b(v);
}

// ---------- slot init ----------
__global__ __launch_bounds__(256) void k_init(const float* __restrict__ sm,
                                              const float* __restrict__ slv,
                                              const float* __restrict__ noise,
                                              float* __restrict__ slots) {
    int idx = blockIdx.x * 256 + threadIdx.x; // 131072
    int d = idx & 255;
    slots[idx] = sm[d] + expf(slv[d]) * noise[idx];
}

// ---------- fused LN(inputs) + K/V projection ----------
// B fragments loaded DIRECTLY global->VGPR (W3 L2-resident); barrier-free MFMA loop.
// Single 32KB restage buffer, two epilogue passes (K then V) -> LDS 34.8KB total,
// 4 blocks/CU eligible.  launch_bounds min-waves=2 so the allocator keeps the full
// register budget (min-waves=4 forced VGPR=64 -> acc[4][8] spilled -> 2GB scratch traffic).
__global__ __launch_bounds__(256, 2) void k_kv(
    const float* __restrict__ x, const float* __restrict__ lnw, const float* __restrict__ lnb,
    const unsigned short* __restrict__ W3, const float* __restrict__ bk, const float* __restrict__ bv,
    unsigned short* __restrict__ Kb, unsigned short* __restrict__ Vb) {
    __shared__ __align__(16) unsigned short sh[16384];  // 32KB: A frags, then repK, then repV
    __shared__ __align__(16) float bL[512];             // 2KB biases
    unsigned short* As = sh;
    int t = threadIdx.x;
    int w = t >> 6, lane = t & 63;
    int p = lane & 15, q = lane >> 4;

    if (t < 128) {
        float4 bb = (t < 64) ? ((const float4*)bk)[t] : ((const float4*)bv)[t - 64];
        *(float4*)&bL[t * 4] = bb;
    }

    // ---- LN(x) -> As (bf16, xor-swizzled A fragments) ----
    float4 lw  = ((const float4*)lnw)[lane];
    float4 lbv = ((const float4*)lnb)[lane];
    float4 xv[16];
    const float* xbase = x + ((size_t)blockIdx.x * 64 + w * 16) * 256;
    #pragma unroll
    for (int i = 0; i < 16; ++i) xv[i] = ((const float4*)(xbase + i * 256))[lane];
    int kcw = lane >> 3, qw = (lane >> 1) & 3, j0 = (lane & 1) * 4;
    #pragma unroll
    for (int i = 0; i < 16; ++i) {
        float4 v = xv[i];
        float s0 = v.x + v.y + v.z + v.w;
        float s1 = v.x * v.x + v.y * v.y + v.z * v.z + v.w * v.w;
        #pragma unroll
        for (int o = 1; o < 64; o <<= 1) { s0 += __shfl_xor(s0, o); s1 += __shfl_xor(s1, o); }
        float mean = s0 * (1.0f / 256.0f);
        float var  = s1 * (1.0f / 256.0f) - mean * mean;
        float rstd = rsqrtf(var + LN_EPS);
        ushort4 pk;
        pk.x = f2b((v.x - mean) * rstd * lw.x + lbv.x);
        pk.y = f2b((v.y - mean) * rstd * lw.y + lbv.y);
        pk.z = f2b((v.z - mean) * rstd * lw.z + lbv.z);
        pk.w = f2b((v.w - mean) * rstd * lw.w + lbv.w);
        int pos = (qw * 16 + i) ^ kcw;
        *(ushort4*)&As[((w * 8 + kcw) * 64 + pos) * 8 + j0] = pk;
    }
    __syncthreads();

    // ---- barrier-free MFMA main loop ----
    // wave strip: cols [w*128, w*128+128) => half = w>>1, ntl in [(w&1)*8, +8)
    f32x4 acc[4][8];
    f32x4 zero = {0.f, 0.f, 0.f, 0.f};
    #pragma unroll
    for (int rt = 0; rt < 4; ++rt)
        #pragma unroll
        for (int ct = 0; ct < 8; ++ct) acc[rt][ct] = zero;

    const unsigned short* Wb = W3 + (size_t)(w >> 1) * 8192 + (size_t)((w & 1) * 8) * 512 + lane * 8;
    #pragma unroll 2
    for (int kc = 0; kc < 8; ++kc) {
        bf16x8 af[4];
        #pragma unroll
        for (int rt = 0; rt < 4; ++rt)
            af[rt] = *(const bf16x8*)&As[((rt * 8 + kc) * 64 + ((q * 16 + p) ^ kc)) * 8];
        #pragma unroll
        for (int ct = 0; ct < 8; ++ct) {
            bf16x8 bf = *(const bf16x8*)(Wb + (size_t)kc * 16384 + ct * 512);
            #pragma unroll
            for (int rt = 0; rt < 4; ++rt)
                acc[rt][ct] = __builtin_amdgcn_mfma_f32_16x16x32_bf16(af[rt], bf, acc[rt][ct], 0, 0, 0);
        }
    }
    __syncthreads();   // As reads done; safe to overwrite

    unsigned short* rep = As;
    int b_  = blockIdx.x >> 6;
    int n0g = (blockIdx.x & 63) * 64;

    // ---- pass 1: K (cols 0..255, owned by waves 0,1) ----
    if (w < 2) {
        #pragma unroll
        for (int ct = 0; ct < 8; ++ct) {
            int col = w * 128 + ct * 16 + p;
            float bias = bL[col];
            int hl = col >> 5, dh = col & 31;
            #pragma unroll
            for (int rt = 0; rt < 4; ++rt) {
                #pragma unroll
                for (int r = 0; r < 4; ++r) {
                    int nl = rt * 16 + q * 4 + r;
                    rep[(hl * 64 + nl) * 32 + dh] = f2b(acc[rt][ct][r] + bias);
                }
            }
        }
    }
    __syncthreads();
    #pragma unroll
    for (int i = 0; i < 8; ++i) {
        uint4 vd = *(const uint4*)&rep[(i * 256 + t) * 8];
        *(uint4*)(Kb + (((size_t)b_ * 8 + i) * 4096 + n0g) * 32 + t * 8) = vd;
    }
    __syncthreads();

    // ---- pass 2: V (cols 256..511, owned by waves 2,3), even-XOR chunk swizzle ----
    if (w >= 2) {
        #pragma unroll
        for (int ct = 0; ct < 8; ++ct) {
            int vrow = (w - 2) * 128 + ct * 16 + p;
            float bias = bL[256 + vrow];
            #pragma unroll
            for (int rt = 0; rt < 4; ++rt) {
                int chunk = (rt * 4 + q) ^ (p & 14);
                ushort4 pk;
                pk.x = f2b(acc[rt][ct][0] + bias);
                pk.y = f2b(acc[rt][ct][1] + bias);
                pk.z = f2b(acc[rt][ct][2] + bias);
                pk.w = f2b(acc[rt][ct][3] + bias);
                *(ushort4*)&rep[vrow * 64 + chunk * 4] = pk;
            }
        }
    }
    __syncthreads();
    #pragma unroll
    for (int i = 0; i < 8; ++i) {
        int vrow = i * 32 + (t >> 3);
        int c16 = t & 7;
        uint4 vd = *(const uint4*)&rep[vrow * 64 + ((2 * c16) ^ (vrow & 14)) * 4];
        *(uint4*)(Vb + ((size_t)(b_ * 8 + (vrow >> 5)) * 32 + (vrow & 31)) * 4096 + n0g + c16 * 8) = vd;
    }
}

// ---------- q projection ----------
__global__ __launch_bounds__(256) void k_q(
    const float* __restrict__ slots, const float* __restrict__ lnw, const float* __restrict__ lnb,
    const float* __restrict__ wq, const float* __restrict__ bq, float* __restrict__ qg) {
    __shared__ float sln[256];
    __shared__ float red[8];
    int t = threadIdx.x;
    int row = blockIdx.x;
    float v = slots[(size_t)row * 256 + t];
    float s0 = v, s1 = v * v;
    #pragma unroll
    for (int off = 1; off < 64; off <<= 1) { s0 += __shfl_xor(s0, off); s1 += __shfl_xor(s1, off); }
    if ((t & 63) == 0) { red[t >> 6] = s0; red[4 + (t >> 6)] = s1; }
    __syncthreads();
    float ts0 = red[0] + red[1] + red[2] + red[3];
    float ts1 = red[4] + red[5] + red[6] + red[7];
    float mean = ts0 * (1.f / 256.f);
    float var  = ts1 * (1.f / 256.f) - mean * mean;
    float rstd = rsqrtf(var + LN_EPS);
    sln[t] = (v - mean) * rstd * lnw[t] + lnb[t];
    __syncthreads();
    float acc = bq[t];
    #pragma unroll 4
    for (int k = 0; k < 256; ++k) acc += sln[k] * wq[k * 256 + t];
    int b = row >> 3, sl = row & 7;
    qg[(size_t)b * 2048 + (t >> 5) * 256 + sl * 32 + (t & 31)] = acc;
}

// ---------- attention sweep: MFMA QK^T (swapped) + MFMA PV ----------
// grid 2048 = bh(512) x chunk(4); 256 threads (4 waves); wave handles 256 n (8 prs).
// Cross-block partials: upd_part[bh][4][256], rowsum_part[bh][4][8] (summed in k_gA).
__global__ __launch_bounds__(256) void k_attn(
    const unsigned short* __restrict__ Kg, const unsigned short* __restrict__ VTg,
    const float* __restrict__ qg, float* __restrict__ upd_part, float* __restrict__ rowsum_part,
    float* __restrict__ attn_out, int last) {
    __shared__ float supd[4][256];
    __shared__ float srs[4][8];
    int t = threadIdx.x;
    int w = t >> 6, lane = t & 63;
    int c = lane & 15;     // QK-C col = slot s ; PV A row = d ; PV-C col = s
    int g = lane >> 4;     // lane group

    int bh = blockIdx.x >> 2;
    int chunk = blockIdx.x & 3;
    const unsigned short* Kbh = Kg  + (size_t)bh * 4096 * 32;
    const unsigned short* Vbh = VTg + (size_t)bh * 32 * 4096;

    // Q B-fragment: lane holds Q[s=c][d=g*8+j], bf16 hi+lo split; zero for s>=8.
    bf16x8 qhi = {0,0,0,0,0,0,0,0};
    bf16x8 qlo = {0,0,0,0,0,0,0,0};
    if (c < 8) {
        const float* qp = qg + (size_t)bh * 256 + c * 32 + g * 8;
        #pragma unroll
        for (int j = 0; j < 8; ++j) {
            float qv = qp[j];
            unsigned short hb = f2b(qv);
            qhi[j] = (short)hb;
            qlo[j] = (short)f2b(qv - b2f(hb));
        }
    }

    f32x4 zero = {0.f, 0.f, 0.f, 0.f};
    f32x4 accL = zero, accH = zero;
    float rs = 0.f;
    int nb0 = chunk * 1024 + w * 256;

    #pragma unroll 2
    for (int pr = 0; pr < 8; ++pr) {
        int base = nb0 + pr * 32;
        bf16x8 k0 = *(const bf16x8*)(Kbh + (size_t)(base + c) * 32 + g * 8);
        bf16x8 k1 = *(const bf16x8*)(Kbh + (size_t)(base + 16 + c) * 32 + g * 8);
        const unsigned short* vlo = Vbh + (size_t)c * 4096 + base + g * 4;
        const unsigned short* vhi = Vbh + (size_t)(c + 16) * 4096 + base + g * 4;
        union { ushort4 h[2]; bf16x8 v; } V0, V1;
        V0.h[0] = *(const ushort4*)vlo;
        V0.h[1] = *(const ushort4*)(vlo + 16);
        V1.h[0] = *(const ushort4*)vhi;
        V1.h[1] = *(const ushort4*)(vhi + 16);

        f32x4 s0 = __builtin_amdgcn_mfma_f32_16x16x32_bf16(k0, qhi, zero, 0, 0, 0);
        s0 = __builtin_amdgcn_mfma_f32_16x16x32_bf16(k0, qlo, s0, 0, 0, 0);
        f32x4 s1 = __builtin_amdgcn_mfma_f32_16x16x32_bf16(k1, qhi, zero, 0, 0, 0);
        s1 = __builtin_amdgcn_mfma_f32_16x16x32_bf16(k1, qlo, s1, 0, 0, 0);

        float d0[4], d1[4];
        #pragma unroll
        for (int r = 0; r < 4; ++r) { d0[r] = s0[r] * SCALE; d1[r] = s1[r] * SCALE; }
        float m = fmaxf(fmaxf(fmaxf(d0[0], d0[1]), fmaxf(d0[2], d0[3])),
                        fmaxf(fmaxf(d1[0], d1[1]), fmaxf(d1[2], d1[3])));
        m = fmaxf(m, __shfl_xor(m, 1));
        m = fmaxf(m, __shfl_xor(m, 2));
        m = fmaxf(m, __shfl_xor(m, 4));
        m = fmaxf(m, __shfl_xor(m, 8));
        float a0[4], a1[4];
        #pragma unroll
        for (int r = 0; r < 4; ++r) {
            float e0 = __expf(d0[r] - m);
            float e1 = __expf(d1[r] - m);
            float t0 = e0;
            t0 += __shfl_xor(t0, 1); t0 += __shfl_xor(t0, 2); t0 += __shfl_xor(t0, 4);
            float t1 = e1;
            t1 += __shfl_xor(t1, 1); t1 += __shfl_xor(t1, 2); t1 += __shfl_xor(t1, 4);
            a0[r] = e0 * (1.0f / t0) + EPS_ATTN;
            a1[r] = e1 * (1.0f / t1) + EPS_ATTN;
            rs += a0[r] + a1[r];
        }
        if (last && c < 8) {
            float4 st0 = {a0[0], a0[1], a0[2], a0[3]};
            float4 st1 = {a1[0], a1[1], a1[2], a1[3]};
            float* ap = attn_out + ((size_t)bh * 8 + c) * 4096 + base + g * 4;
            *(float4*)ap = st0;
            *(float4*)(ap + 16) = st1;
        }
        bf16x8 pah, pal;
        float af[8] = {a0[0], a0[1], a0[2], a0[3], a1[0], a1[1], a1[2], a1[3]};
        #pragma unroll
        for (int j = 0; j < 8; ++j) {
            unsigned short hb = f2b(af[j]);
            pah[j] = (short)hb;
            pal[j] = (short)f2b(af[j] - b2f(hb));
        }
        accL = __builtin_amdgcn_mfma_f32_16x16x32_bf16(V0.v, pah, accL, 0, 0, 0);
        accL = __builtin_amdgcn_mfma_f32_16x16x32_bf16(V0.v, pal, accL, 0, 0, 0);
        accH = __builtin_amdgcn_mfma_f32_16x16x32_bf16(V1.v, pah, accH, 0, 0, 0);
        accH = __builtin_amdgcn_mfma_f32_16x16x32_bf16(V1.v, pal, accH, 0, 0, 0);
    }

    rs += __shfl_xor(rs, 16);
    rs += __shfl_xor(rs, 32);
    if (lane < 8) srs[w][lane] = rs;
    if (c < 8) {
        float* up = &supd[w][c * 32 + g * 4];
        up[0]  = accL[0]; up[1]  = accL[1]; up[2]  = accL[2]; up[3]  = accL[3];
        up[16] = accH[0]; up[17] = accH[1]; up[18] = accH[2]; up[19] = accH[3];
    }
    __syncthreads();
    {
        float v = supd[0][t] + supd[1][t] + supd[2][t] + supd[3][t];
        upd_part[((size_t)bh * 4 + chunk) * 256 + t] = v;
    }
    if (t < 8) {
        float v = srs[0][t] + srs[1][t] + srs[2][t] + srs[3][t];
        rowsum_part[((size_t)bh * 4 + chunk) * 8 + t] = v;
    }
}

// ========== slot-update stage kernels (col-split, LDS row-broadcast) ==========
// Stage A: O = U @ wo + bo; sums the 4 attn partials, emits rowsum_tot (cc==0).
__global__ __launch_bounds__(256) void k_gA(
    const float* __restrict__ upd_part, const float* __restrict__ rowsum_part,
    const float* __restrict__ wo, const float* __restrict__ bo,
    float* __restrict__ O, float* __restrict__ rowsum_tot) {
    __shared__ float Ul[8][256];
    __shared__ float Pp[4][8][64];
    int t = threadIdx.x;
    int b = blockIdx.x >> 2, cc = blockIdx.x & 3;
    int colbase = cc * 64;
    {
        int r = t >> 5, d0 = (t & 31) * 8;
        int h = (t & 31) >> 2;      // d0 >> 5
        float rsum = 0.f;
        #pragma unroll
        for (int ch = 0; ch < 4; ++ch)
            rsum += rowsum_part[((size_t)(b * 8 + h) * 4 + ch) * 8 + r];
        float inv = 1.0f / fmaxf(rsum, 1e-12f);
        float u[8] = {0.f,0.f,0.f,0.f,0.f,0.f,0.f,0.f};
        #pragma unroll
        for (int ch = 0; ch < 4; ++ch) {
            const float* up = upd_part + ((size_t)(b * 8 + h) * 4 + ch) * 256 + r * 32 + (d0 & 31);
            float4 u0 = *(const float4*)up;
            float4 u1 = *(const float4*)(up + 4);
            u[0] += u0.x; u[1] += u0.y; u[2] += u0.z; u[3] += u0.w;
            u[4] += u1.x; u[5] += u1.y; u[6] += u1.z; u[7] += u1.w;
        }
        #pragma unroll
        for (int i = 0; i < 8; ++i) Ul[r][d0 + i] = u[i] * inv;
        if (cc == 0 && (t & 3) == 0) rowsum_tot[(b * 8 + h) * 8 + r] = rsum;
    }
    __syncthreads();
    int c = t & 63, kq = t >> 6;
    float acc[8] = {0.f,0.f,0.f,0.f,0.f,0.f,0.f,0.f};
    const float* wp = wo + (size_t)(kq * 64) * 256 + colbase + c;
    #pragma unroll 16
    for (int k = 0; k < 64; ++k) {
        float wv_ = wp[(size_t)k * 256];
        int kk = kq * 64 + k;
        #pragma unroll
        for (int r = 0; r < 8; ++r) acc[r] += Ul[r][kk] * wv_;
    }
    #pragma unroll
    for (int r = 0; r < 8; ++r) Pp[kq][r][c] = acc[r];
    __syncthreads();
    #pragma unroll
    for (int j = 0; j < 2; ++j) {
        int o = t * 2 + j;
        int r = o >> 6, c2 = o & 63;
        float v = Pp[0][r][c2] + Pp[1][r][c2] + Pp[2][r][c2] + Pp[3][r][c2] + bo[colbase + c2];
        O[(size_t)(b * 8 + r) * 256 + colbase + c2] = v;
    }
}

__global__ __launch_bounds__(256) void k_gB(
    const float* __restrict__ O, const float* __restrict__ slin,
    const float* __restrict__ wih, const float* __restrict__ bih,
    const float* __restrict__ whh, const float* __restrict__ bhh,
    float* __restrict__ gcomb, float* __restrict__ xn, float* __restrict__ hn) {
    __shared__ float Ol[8][256], Hl[8][256];
    __shared__ float Px[2][8][128], Ph[2][8][128];
    int t = threadIdx.x;
    int b = blockIdx.x / 6, cc = blockIdx.x % 6;
    int colbase = cc * 128;
    {
        int r = t >> 5, d0 = (t & 31) * 8;
        const float* op = O + (size_t)(b * 8 + r) * 256 + d0;
        const float* hp = slin + (size_t)(b * 8 + r) * 256 + d0;
        *(float4*)&Ol[r][d0]     = *(const float4*)op;
        *(float4*)&Ol[r][d0 + 4] = *(const float4*)(op + 4);
        *(float4*)&Hl[r][d0]     = *(const float4*)hp;
        *(float4*)&Hl[r][d0 + 4] = *(const float4*)(hp + 4);
    }
    __syncthreads();
    int c = t & 127, kh = t >> 7;
    float ax[8] = {0.f,0.f,0.f,0.f,0.f,0.f,0.f,0.f};
    float ah[8] = {0.f,0.f,0.f,0.f,0.f,0.f,0.f,0.f};
    const float* wxp = wih + (size_t)(kh * 128) * 768 + colbase + c;
    const float* whp = whh + (size_t)(kh * 128) * 768 + colbase + c;
    #pragma unroll 8
    for (int k = 0; k < 128; ++k) {
        float wx = wxp[(size_t)k * 768];
        float wh = whp[(size_t)k * 768];
        int kk = kh * 128 + k;
        #pragma unroll
        for (int r = 0; r < 8; ++r) { ax[r] += Ol[r][kk] * wx; ah[r] += Hl[r][kk] * wh; }
    }
    #pragma unroll
    for (int r = 0; r < 8; ++r) { Px[kh][r][c] = ax[r]; Ph[kh][r][c] = ah[r]; }
    __syncthreads();
    #pragma unroll
    for (int j = 0; j < 4; ++j) {
        int o = t * 4 + j;               // [0,1024)
        int r = o >> 7, c2 = o & 127;
        int cg = colbase + c2;
        int row = b * 8 + r;
        float vx = Px[0][r][c2] + Px[1][r][c2] + bih[cg];
        float vh = Ph[0][r][c2] + Ph[1][r][c2] + bhh[cg];
        if (cg < 512) {
            gcomb[(size_t)row * 512 + cg] = vx + vh;
        } else {
            xn[(size_t)row * 256 + cg - 512] = vx;
            hn[(size_t)row * 256 + cg - 512] = vh;
        }
    }
}

__global__ __launch_bounds__(256) void k_gC(
    const float* __restrict__ gcomb, const float* __restrict__ xn, const float* __restrict__ hn,
    const float* __restrict__ slin, const float* __restrict__ lnfw, const float* __restrict__ lnfb,
    float* __restrict__ slout, float* __restrict__ F) {
    __shared__ float red[8];
    int t = threadIdx.x, row = blockIdx.x;
    float a_r = gcomb[(size_t)row * 512 + t];
    float a_z = gcomb[(size_t)row * 512 + 256 + t];
    float xnv = xn[(size_t)row * 256 + t];
    float hnv = hn[(size_t)row * 256 + t];
    float hp  = slin[(size_t)row * 256 + t];
    float rg = 1.f / (1.f + expf(-a_r));
    float zg = 1.f / (1.f + expf(-a_z));
    float ng = tanhf(xnv + rg * hnv);
    float s1 = (1.f - zg) * ng + zg * hp;
    slout[(size_t)row * 256 + t] = s1;
    float s0 = s1, sq = s1 * s1;
    #pragma unroll
    for (int o = 1; o < 64; o <<= 1) { s0 += __shfl_xor(s0, o); sq += __shfl_xor(sq, o); }
    if ((t & 63) == 0) { red[t >> 6] = s0; red[4 + (t >> 6)] = sq; }
    __syncthreads();
    float ts0 = red[0] + red[1] + red[2] + red[3];
    float ts1 = red[4] + red[5] + red[6] + red[7];
    float mean = ts0 * (1.f / 256.f);
    float var  = ts1 * (1.f / 256.f) - mean * mean;
    float rstd = rsqrtf(var + LN_EPS);
    F[(size_t)row * 256 + t] = (s1 - mean) * rstd * lnfw[t] + lnfb[t];
}

__global__ __launch_bounds__(256) void k_gD(
    const float* __restrict__ F, const float* __restrict__ w1, const float* __restrict__ b1,
    float* __restrict__ H1) {
    __shared__ float Fl[8][256];
    __shared__ float Pp[4][8][64];
    int t = threadIdx.x;
    int b = blockIdx.x >> 2, cc = blockIdx.x & 3;
    int colbase = cc * 64;
    {
        int r = t >> 5, d0 = (t & 31) * 8;
        const float* fp = F + (size_t)(b * 8 + r) * 256 + d0;
        *(float4*)&Fl[r][d0]     = *(const float4*)fp;
        *(float4*)&Fl[r][d0 + 4] = *(const float4*)(fp + 4);
    }
    __syncthreads();
    int c = t & 63, kq = t >> 6;
    float acc[8] = {0.f,0.f,0.f,0.f,0.f,0.f,0.f,0.f};
    const float* wp = w1 + (size_t)(kq * 64) * 256 + colbase + c;
    #pragma unroll 16
    for (int k = 0; k < 64; ++k) {
        float wv_ = wp[(size_t)k * 256];
        int kk = kq * 64 + k;
        #pragma unroll
        for (int r = 0; r < 8; ++r) acc[r] += Fl[r][kk] * wv_;
    }
    #pragma unroll
    for (int r = 0; r < 8; ++r) Pp[kq][r][c] = acc[r];
    __syncthreads();
    #pragma unroll
    for (int j = 0; j < 2; ++j) {
        int o = t * 2 + j;
        int r = o >> 6, c2 = o & 63;
        float v = Pp[0][r][c2] + Pp[1][r][c2] + Pp[2][r][c2] + Pp[3][r][c2] + b1[colbase + c2];
        H1[(size_t)(b * 8 + r) * 256 + colbase + c2] = fmaxf(v, 0.f);
    }
}

__global__ __launch_bounds__(256) void k_gE(
    const float* __restrict__ H1, const float* __restrict__ w2, const float* __restrict__ b2,
    float* __restrict__ slout) {
    __shared__ float Hl[8][256];
    __shared__ float Pp[4][8][64];
    int t = threadIdx.x;
    int b = blockIdx.x >> 2, cc = blockIdx.x & 3;
    int colbase = cc * 64;
    {
        int r = t >> 5, d0 = (t & 31) * 8;
        const float* hp = H1 + (size_t)(b * 8 + r) * 256 + d0;
        *(float4*)&Hl[r][d0]     = *(const float4*)hp;
        *(float4*)&Hl[r][d0 + 4] = *(const float4*)(hp + 4);
    }
    __syncthreads();
    int c = t & 63, kq = t >> 6;
    float acc[8] = {0.f,0.f,0.f,0.f,0.f,0.f,0.f,0.f};
    const float* wp = w2 + (size_t)(kq * 64) * 256 + colbase + c;
    #pragma unroll 16
    for (int k = 0; k < 64; ++k) {
        float wv_ = wp[(size_t)k * 256];
        int kk = kq * 64 + k;
        #pragma unroll
        for (int r = 0; r < 8; ++r) acc[r] += Hl[r][kk] * wv_;
    }
    #pragma unroll
    for (int r = 0; r < 8; ++r) Pp[kq][r][c] = acc[r];
    __syncthreads();
    #pragma unroll
    for (int j = 0; j < 2; ++j) {
        int o = t * 2 + j;
        int r = o >> 6, c2 = o & 63;
        size_t idx = (size_t)(b * 8 + r) * 256 + colbase + c2;
        float v = Pp[0][r][c2] + Pp[1][r][c2] + Pp[2][r][c2] + Pp[3][r][c2] + b2[colbase + c2];
        slout[idx] = slout[idx] + v;
    }
}

// ---------- final attn normalization (float4) ----------
__global__ __launch_bounds__(256) void k_scale(float* __restrict__ attn, const float* __restrict__ rowsum_tot) {
    size_t i4 = ((size_t)blockIdx.x * 256 + threadIdx.x) * 4;
    int row = (int)(i4 >> 12);
    float inv = 1.0f / fmaxf(rowsum_tot[row], 1e-12f);
    float4 v = *(float4*)(attn + i4);
    v.x *= inv; v.y *= inv; v.z *= inv; v.w *= inv;
    *(float4*)(attn + i4) = v;
}

extern "C" void kernel_launch(void* const* d_in, const int* in_sizes, int n_in,
                              void* d_out, int out_size, void* d_ws, size_t ws_size,
                              hipStream_t stream) {
    const float* inputs = (const float*)d_in[0];
    const float* noise  = (const float*)d_in[1];
    const float* sm     = (const float*)d_in[2];
    const float* slv    = (const float*)d_in[3];
    const float* wq     = (const float*)d_in[4];
    const float* bq     = (const float*)d_in[5];
    const float* wk     = (const float*)d_in[6];
    const float* bk     = (const float*)d_in[7];
    const float* wv     = (const float*)d_in[8];
    const float* bv     = (const float*)d_in[9];
    const float* wo     = (const float*)d_in[10];
    const float* bo     = (const float*)d_in[11];
    const float* wih    = (const float*)d_in[12];
    const float* bih    = (const float*)d_in[13];
    const float* whh    = (const float*)d_in[14];
    const float* bhh    = (const float*)d_in[15];
    const float* w1     = (const float*)d_in[16];
    const float* b1     = (const float*)d_in[17];
    const float* w2     = (const float*)d_in[18];
    const float* b2     = (const float*)d_in[19];
    const float* lniw   = (const float*)d_in[20];
    const float* lnib   = (const float*)d_in[21];
    const float* lnsw   = (const float*)d_in[22];
    const float* lnsb   = (const float*)d_in[23];
    const float* lnfw   = (const float*)d_in[24];
    const float* lnfb   = (const float*)d_in[25];

    char* ws = (char*)d_ws;
    unsigned short* Kb = (unsigned short*)ws;                         // 134,217,728  [bh][n][32]
    unsigned short* Vb = (unsigned short*)(ws + 134217728ull);        // 134,217,728  [bh][d][4096] (transposed)
    float* slotsA  = (float*)(ws + 268435456ull);                     // 524,288
    float* slotsB  = (float*)(ws + 268959744ull);                     // 524,288
    float* Rr      = (float*)(ws + 269484032ull);                     // 524,288  (qg / F)
    float* Pr      = (float*)(ws + 270008320ull);                     // 524,288  (W3 / O)
    float* Qr      = (float*)(ws + 270532608ull);                     // 2,097,152 (upd_part / gcomb|xn|hn / H1)
    float* rowsum_part = (float*)(ws + 272629760ull);                 // 65,536
    float* rowsum_tot  = (float*)(ws + 273154048ull);                 // 16,384
    unsigned short* W3 = (unsigned short*)Pr;
    float* O_  = Pr;
    float* upd_part = Qr;                 // 512x4x256 (attn -> gA, dead by gB)
    float* gcomb = Qr;                    // 512x512
    float* xn = Qr + 262144;              // 512x256
    float* hn = Qr + 393216;              // 512x256
    float* H1 = Qr;                       // 512x256 (aliases gcomb, gB->gC dead by gD)
    float* qg = Rr;
    float* F_ = Rr;

    float* out_slots = (float*)d_out;            // [64,8,256]
    float* attn_out  = (float*)d_out + 131072;   // [64,8,8,4096]

    k_prep<<<512, 256, 0, stream>>>(wk, wv, W3);
    k_init<<<512, 256, 0, stream>>>(sm, slv, noise, slotsA);
    k_kv<<<4096, 256, 0, stream>>>(inputs, lniw, lnib, W3, bk, bv, Kb, Vb);
    for (int it = 0; it < 3; ++it) {
        int last = (it == 2);
        float* sl_in  = (it == 0) ? slotsA : ((it == 1) ? slotsB : slotsA);
        float* sl_out = (it == 0) ? slotsB : ((it == 1) ? slotsA : out_slots);
        k_q<<<512, 256, 0, stream>>>(sl_in, lnsw, lnsb, wq, bq, qg);
        k_attn<<<2048, 256, 0, stream>>>(Kb, Vb, qg, upd_part, rowsum_part, attn_out, last);
        k_gA<<<256, 256, 0, stream>>>(upd_part, rowsum_part, wo, bo, O_, rowsum_tot);
        k_gB<<<384, 256, 0, stream>>>(O_, sl_in, wih, bih, whh, bhh, gcomb, xn, hn);
        k_gC<<<512, 256, 0, stream>>>(gcomb, xn, hn, sl_in, lnfw, lnfb, sl_out, F_);
        k_gD<<<256, 256, 0, stream>>>(F_, w1, b1, H1);
        k_gE<<<256, 256, 0, stream>>>(H1, w2, b2, sl_out);
    }
    k_scale<<<16384, 256, 0, stream>>>(attn_out, rowsum_tot);
}

// Round 5
// 1024.909 us; speedup vs baseline: 1.3736x; 1.0718x over previous
//
#include <hip/hip_runtime.h>
#include <stdint.h>

// ---------- helpers ----------
typedef __attribute__((ext_vector_type(8))) short bf16x8;
typedef __attribute__((ext_vector_type(4))) float f32x4;

__device__ __forceinline__ float b2f(unsigned short s) {
    unsigned int u = ((unsigned int)s) << 16;
    return __builtin_bit_cast(float, u);
}
__device__ __forceinline__ unsigned short f2b(float f) {
    unsigned int u = __builtin_bit_cast(unsigned int, f);
    u += 0x7FFFu + ((u >> 16) & 1u);   // RNE
    return (unsigned short)(u >> 16);
}

#define EPS_ATTN 1e-8f
#define LN_EPS 1e-5f
#define SCALE 0.0625f  // 256^-0.5

// ---------- prep: W3 in MFMA B-fragment order ----------
__global__ __launch_bounds__(256) void k_prep(const float* __restrict__ wk,
                                              const float* __restrict__ wv,
                                              unsigned short* __restrict__ W3) {
    int g = blockIdx.x * 256 + threadIdx.x;   // 131072
    int j = g & 7;
    int f = (g >> 3) & 1023;
    int stage = g >> 13;
    int p = f & 15, qq = (f >> 4) & 3, ntl = f >> 6;
    int kc = stage >> 1, half_ = stage & 1;
    int k = kc * 32 + qq * 8 + j;
    int n = half_ * 256 + ntl * 16 + p;
    float v = (n < 256) ? wk[k * 256 + n] : wv[k * 256 + (n - 256)];
    W3[g] = f2b(v);
}

// ---------- slot init ----------
__global__ __launch_bounds__(256) void k_init(const float* __restrict__ sm,
                                              const float* __restrict__ slv,
                                              const float* __restrict__ noise,
                                              float* __restrict__ slots) {
    int idx = blockIdx.x * 256 + threadIdx.x; // 131072
    int d = idx & 255;
    slots[idx] = sm[d] + expf(slv[d]) * noise[idx];
}

// ---------- fused LN(inputs) + K/V projection ----------
// Barrier-free MFMA loop (B frags direct global->VGPR from L2-resident W3).
// Wave w owns K cols [w*64,+64) AND V rows [w*64,+64), so BOTH epilogue staging
// passes use all 4 waves. Single 32KB restage buffer -> LDS 34.8KB, 4 blk/CU.
// K restage chunk-XOR swizzled (8-way -> 4-way bank conflict).
__global__ __launch_bounds__(256, 2) void k_kv(
    const float* __restrict__ x, const float* __restrict__ lnw, const float* __restrict__ lnb,
    const unsigned short* __restrict__ W3, const float* __restrict__ bk, const float* __restrict__ bv,
    unsigned short* __restrict__ Kb, unsigned short* __restrict__ Vb) {
    __shared__ __align__(16) unsigned short sh[16384];  // 32KB: A frags, then repK, then repV
    __shared__ __align__(16) float bL[512];             // 2KB biases
    unsigned short* As = sh;
    int t = threadIdx.x;
    int w = t >> 6, lane = t & 63;
    int p = lane & 15, q = lane >> 4;

    if (t < 128) {
        float4 bb = (t < 64) ? ((const float4*)bk)[t] : ((const float4*)bv)[t - 64];
        *(float4*)&bL[t * 4] = bb;
    }

    // ---- LN(x) -> As (bf16, xor-swizzled A fragments) ----
    float4 lw  = ((const float4*)lnw)[lane];
    float4 lbv = ((const float4*)lnb)[lane];
    float4 xv[16];
    const float* xbase = x + ((size_t)blockIdx.x * 64 + w * 16) * 256;
    #pragma unroll
    for (int i = 0; i < 16; ++i) xv[i] = ((const float4*)(xbase + i * 256))[lane];
    int kcw = lane >> 3, qw = (lane >> 1) & 3, j0 = (lane & 1) * 4;
    #pragma unroll
    for (int i = 0; i < 16; ++i) {
        float4 v = xv[i];
        float s0 = v.x + v.y + v.z + v.w;
        float s1 = v.x * v.x + v.y * v.y + v.z * v.z + v.w * v.w;
        #pragma unroll
        for (int o = 1; o < 64; o <<= 1) { s0 += __shfl_xor(s0, o); s1 += __shfl_xor(s1, o); }
        float mean = s0 * (1.0f / 256.0f);
        float var  = s1 * (1.0f / 256.0f) - mean * mean;
        float rstd = rsqrtf(var + LN_EPS);
        ushort4 pk;
        pk.x = f2b((v.x - mean) * rstd * lw.x + lbv.x);
        pk.y = f2b((v.y - mean) * rstd * lw.y + lbv.y);
        pk.z = f2b((v.z - mean) * rstd * lw.z + lbv.z);
        pk.w = f2b((v.w - mean) * rstd * lw.w + lbv.w);
        int pos = (qw * 16 + i) ^ kcw;
        *(ushort4*)&As[((w * 8 + kcw) * 64 + pos) * 8 + j0] = pk;
    }
    __syncthreads();

    // ---- barrier-free MFMA main loop ----
    // ct 0..3 -> K cols w*64+ct*16+p (W3 half 0, ntl=w*4+ct)
    // ct 4..7 -> V rows w*64+(ct-4)*16+p (W3 half 1, ntl=w*4+(ct-4))
    f32x4 acc[4][8];
    f32x4 zero = {0.f, 0.f, 0.f, 0.f};
    #pragma unroll
    for (int rt = 0; rt < 4; ++rt)
        #pragma unroll
        for (int ct = 0; ct < 8; ++ct) acc[rt][ct] = zero;

    const unsigned short* WbL = W3 + lane * 8;
    #pragma unroll 2
    for (int kc = 0; kc < 8; ++kc) {
        bf16x8 af[4];
        #pragma unroll
        for (int rt = 0; rt < 4; ++rt)
            af[rt] = *(const bf16x8*)&As[((rt * 8 + kc) * 64 + ((q * 16 + p) ^ kc)) * 8];
        #pragma unroll
        for (int ct = 0; ct < 8; ++ct) {
            int half_ = ct >> 2;
            int ntl = w * 4 + (ct & 3);
            bf16x8 bf = *(const bf16x8*)(WbL + (size_t)kc * 16384 + half_ * 8192 + ntl * 512);
            #pragma unroll
            for (int rt = 0; rt < 4; ++rt)
                acc[rt][ct] = __builtin_amdgcn_mfma_f32_16x16x32_bf16(af[rt], bf, acc[rt][ct], 0, 0, 0);
        }
    }
    __syncthreads();   // As reads done; safe to overwrite

    unsigned short* rep = As;
    int b_  = blockIdx.x >> 6;
    int n0g = (blockIdx.x & 63) * 64;

    // ---- pass 1: K stage (ALL waves; wave w covers K cols w*64..w*64+63) ----
    #pragma unroll
    for (int ct = 0; ct < 4; ++ct) {
        int col = w * 64 + ct * 16 + p;
        float bias = bL[col];
        int hl = col >> 5, dh = col & 31;
        int dlo = dh & 7, dch = dh >> 3;
        int dchs = dch ^ q;                     // chunk-XOR swizzle (q = (nl>>2)&3)
        #pragma unroll
        for (int rt = 0; rt < 4; ++rt) {
            #pragma unroll
            for (int r = 0; r < 4; ++r) {
                int nl = rt * 16 + q * 4 + r;
                rep[(hl * 64 + nl) * 32 + dchs * 8 + dlo] = f2b(acc[rt][ct][r] + bias);
            }
        }
    }
    __syncthreads();
    // K store: reader applies inverse chunk swizzle; global stores fully coalesced
    {
        int nl = t >> 2, dhc = t & 3;
        int swz = (nl >> 2) & 3;
        #pragma unroll
        for (int i = 0; i < 8; ++i) {
            uint4 vd = *(const uint4*)&rep[((i * 64 + nl) * 32) + ((dhc ^ swz) * 8)];
            *(uint4*)(Kb + (((size_t)b_ * 8 + i) * 4096 + n0g + nl) * 32 + dhc * 8) = vd;
        }
    }
    __syncthreads();

    // ---- pass 2: V stage (ALL waves; wave w covers V rows w*64..w*64+63) ----
    #pragma unroll
    for (int ct = 4; ct < 8; ++ct) {
        int vrow = w * 64 + (ct - 4) * 16 + p;
        float bias = bL[256 + vrow];
        #pragma unroll
        for (int rt = 0; rt < 4; ++rt) {
            int chunk = (rt * 4 + q) ^ (p & 14);
            ushort4 pk;
            pk.x = f2b(acc[rt][ct][0] + bias);
            pk.y = f2b(acc[rt][ct][1] + bias);
            pk.z = f2b(acc[rt][ct][2] + bias);
            pk.w = f2b(acc[rt][ct][3] + bias);
            *(ushort4*)&rep[vrow * 64 + chunk * 4] = pk;
        }
    }
    __syncthreads();
    #pragma unroll
    for (int i = 0; i < 8; ++i) {
        int vrow = i * 32 + (t >> 3);
        int c16 = t & 7;
        uint4 vd = *(const uint4*)&rep[vrow * 64 + ((2 * c16) ^ (vrow & 14)) * 4];
        *(uint4*)(Vb + ((size_t)(b_ * 8 + (vrow >> 5)) * 32 + (vrow & 31)) * 4096 + n0g + c16 * 8) = vd;
    }
}

// ---------- q projection ----------
__global__ __launch_bounds__(256) void k_q(
    const float* __restrict__ slots, const float* __restrict__ lnw, const float* __restrict__ lnb,
    const float* __restrict__ wq, const float* __restrict__ bq, float* __restrict__ qg) {
    __shared__ float sln[256];
    __shared__ float red[8];
    int t = threadIdx.x;
    int row = blockIdx.x;
    float v = slots[(size_t)row * 256 + t];
    float s0 = v, s1 = v * v;
    #pragma unroll
    for (int off = 1; off < 64; off <<= 1) { s0 += __shfl_xor(s0, off); s1 += __shfl_xor(s1, off); }
    if ((t & 63) == 0) { red[t >> 6] = s0; red[4 + (t >> 6)] = s1; }
    __syncthreads();
    float ts0 = red[0] + red[1] + red[2] + red[3];
    float ts1 = red[4] + red[5] + red[6] + red[7];
    float mean = ts0 * (1.f / 256.f);
    float var  = ts1 * (1.f / 256.f) - mean * mean;
    float rstd = rsqrtf(var + LN_EPS);
    sln[t] = (v - mean) * rstd * lnw[t] + lnb[t];
    __syncthreads();
    float acc = bq[t];
    #pragma unroll 4
    for (int k = 0; k < 256; ++k) acc += sln[k] * wq[k * 256 + t];
    int b = row >> 3, sl = row & 7;
    qg[(size_t)b * 2048 + (t >> 5) * 256 + sl * 32 + (t & 31)] = acc;
}

// ---------- rowsum pre-pass (last iteration only): QK^T + softmax, rowsum_part out ----------
__global__ __launch_bounds__(256) void k_pre(
    const unsigned short* __restrict__ Kg, const float* __restrict__ qg,
    float* __restrict__ rowsum_part) {
    __shared__ float srs[4][8];
    int t = threadIdx.x;
    int w = t >> 6, lane = t & 63;
    int c = lane & 15, g = lane >> 4;
    int bh = blockIdx.x >> 2;
    int chunk = blockIdx.x & 3;
    const unsigned short* Kbh = Kg + (size_t)bh * 4096 * 32;

    bf16x8 qhi = {0,0,0,0,0,0,0,0};
    bf16x8 qlo = {0,0,0,0,0,0,0,0};
    if (c < 8) {
        const float* qp = qg + (size_t)bh * 256 + c * 32 + g * 8;
        #pragma unroll
        for (int j = 0; j < 8; ++j) {
            float qv = qp[j];
            unsigned short hb = f2b(qv);
            qhi[j] = (short)hb;
            qlo[j] = (short)f2b(qv - b2f(hb));
        }
    }

    f32x4 zero = {0.f, 0.f, 0.f, 0.f};
    float rs = 0.f;
    int nb0 = chunk * 1024 + w * 256;

    #pragma unroll 2
    for (int pr = 0; pr < 8; ++pr) {
        int base = nb0 + pr * 32;
        bf16x8 k0 = *(const bf16x8*)(Kbh + (size_t)(base + c) * 32 + g * 8);
        bf16x8 k1 = *(const bf16x8*)(Kbh + (size_t)(base + 16 + c) * 32 + g * 8);
        f32x4 s0 = __builtin_amdgcn_mfma_f32_16x16x32_bf16(k0, qhi, zero, 0, 0, 0);
        s0 = __builtin_amdgcn_mfma_f32_16x16x32_bf16(k0, qlo, s0, 0, 0, 0);
        f32x4 s1 = __builtin_amdgcn_mfma_f32_16x16x32_bf16(k1, qhi, zero, 0, 0, 0);
        s1 = __builtin_amdgcn_mfma_f32_16x16x32_bf16(k1, qlo, s1, 0, 0, 0);
        float d0[4], d1[4];
        #pragma unroll
        for (int r = 0; r < 4; ++r) { d0[r] = s0[r] * SCALE; d1[r] = s1[r] * SCALE; }
        float m = fmaxf(fmaxf(fmaxf(d0[0], d0[1]), fmaxf(d0[2], d0[3])),
                        fmaxf(fmaxf(d1[0], d1[1]), fmaxf(d1[2], d1[3])));
        m = fmaxf(m, __shfl_xor(m, 1));
        m = fmaxf(m, __shfl_xor(m, 2));
        m = fmaxf(m, __shfl_xor(m, 4));
        m = fmaxf(m, __shfl_xor(m, 8));
        #pragma unroll
        for (int r = 0; r < 4; ++r) {
            float e0 = __expf(d0[r] - m);
            float e1 = __expf(d1[r] - m);
            float t0 = e0;
            t0 += __shfl_xor(t0, 1); t0 += __shfl_xor(t0, 2); t0 += __shfl_xor(t0, 4);
            float t1 = e1;
            t1 += __shfl_xor(t1, 1); t1 += __shfl_xor(t1, 2); t1 += __shfl_xor(t1, 4);
            rs += (e0 * (1.0f / t0) + EPS_ATTN) + (e1 * (1.0f / t1) + EPS_ATTN);
        }
    }
    rs += __shfl_xor(rs, 16);
    rs += __shfl_xor(rs, 32);
    if (lane < 8) srs[w][lane] = rs;
    __syncthreads();
    if (t < 8) {
        rowsum_part[((size_t)bh * 4 + chunk) * 8 + t] =
            srs[0][t] + srs[1][t] + srs[2][t] + srs[3][t];
    }
}

// ---------- attention sweep: MFMA QK^T (swapped) + MFMA PV ----------
// grid 2048 = bh(512) x chunk(4); 256 threads (4 waves); wave handles 256 n (8 prs).
// last=1: attn written NORMALIZED (rowsum_part precomputed by k_pre); rowsum store skipped.
__global__ __launch_bounds__(256) void k_attn(
    const unsigned short* __restrict__ Kg, const unsigned short* __restrict__ VTg,
    const float* __restrict__ qg, float* __restrict__ upd_part, float* __restrict__ rowsum_part,
    float* __restrict__ attn_out, int last) {
    __shared__ float supd[4][256];
    __shared__ float srs[4][8];
    int t = threadIdx.x;
    int w = t >> 6, lane = t & 63;
    int c = lane & 15;     // QK-C col = slot s ; PV A row = d ; PV-C col = s
    int g = lane >> 4;     // lane group

    int bh = blockIdx.x >> 2;
    int chunk = blockIdx.x & 3;
    const unsigned short* Kbh = Kg  + (size_t)bh * 4096 * 32;
    const unsigned short* Vbh = VTg + (size_t)bh * 32 * 4096;

    // Q B-fragment: lane holds Q[s=c][d=g*8+j], bf16 hi+lo split; zero for s>=8.
    bf16x8 qhi = {0,0,0,0,0,0,0,0};
    bf16x8 qlo = {0,0,0,0,0,0,0,0};
    if (c < 8) {
        const float* qp = qg + (size_t)bh * 256 + c * 32 + g * 8;
        #pragma unroll
        for (int j = 0; j < 8; ++j) {
            float qv = qp[j];
            unsigned short hb = f2b(qv);
            qhi[j] = (short)hb;
            qlo[j] = (short)f2b(qv - b2f(hb));
        }
    }
    float ainv = 0.f;
    if (last && c < 8) {
        float rsum = 0.f;
        #pragma unroll
        for (int ch = 0; ch < 4; ++ch) rsum += rowsum_part[((size_t)bh * 4 + ch) * 8 + c];
        ainv = 1.0f / fmaxf(rsum, 1e-12f);
    }

    f32x4 zero = {0.f, 0.f, 0.f, 0.f};
    f32x4 accL = zero, accH = zero;
    float rs = 0.f;
    int nb0 = chunk * 1024 + w * 256;

    #pragma unroll 2
    for (int pr = 0; pr < 8; ++pr) {
        int base = nb0 + pr * 32;
        bf16x8 k0 = *(const bf16x8*)(Kbh + (size_t)(base + c) * 32 + g * 8);
        bf16x8 k1 = *(const bf16x8*)(Kbh + (size_t)(base + 16 + c) * 32 + g * 8);
        const unsigned short* vlo = Vbh + (size_t)c * 4096 + base + g * 4;
        const unsigned short* vhi = Vbh + (size_t)(c + 16) * 4096 + base + g * 4;
        union { ushort4 h[2]; bf16x8 v; } V0, V1;
        V0.h[0] = *(const ushort4*)vlo;
        V0.h[1] = *(const ushort4*)(vlo + 16);
        V1.h[0] = *(const ushort4*)vhi;
        V1.h[1] = *(const ushort4*)(vhi + 16);

        f32x4 s0 = __builtin_amdgcn_mfma_f32_16x16x32_bf16(k0, qhi, zero, 0, 0, 0);
        s0 = __builtin_amdgcn_mfma_f32_16x16x32_bf16(k0, qlo, s0, 0, 0, 0);
        f32x4 s1 = __builtin_amdgcn_mfma_f32_16x16x32_bf16(k1, qhi, zero, 0, 0, 0);
        s1 = __builtin_amdgcn_mfma_f32_16x16x32_bf16(k1, qlo, s1, 0, 0, 0);

        float d0[4], d1[4];
        #pragma unroll
        for (int r = 0; r < 4; ++r) { d0[r] = s0[r] * SCALE; d1[r] = s1[r] * SCALE; }
        float m = fmaxf(fmaxf(fmaxf(d0[0], d0[1]), fmaxf(d0[2], d0[3])),
                        fmaxf(fmaxf(d1[0], d1[1]), fmaxf(d1[2], d1[3])));
        m = fmaxf(m, __shfl_xor(m, 1));
        m = fmaxf(m, __shfl_xor(m, 2));
        m = fmaxf(m, __shfl_xor(m, 4));
        m = fmaxf(m, __shfl_xor(m, 8));
        float a0[4], a1[4];
        #pragma unroll
        for (int r = 0; r < 4; ++r) {
            float e0 = __expf(d0[r] - m);
            float e1 = __expf(d1[r] - m);
            float t0 = e0;
            t0 += __shfl_xor(t0, 1); t0 += __shfl_xor(t0, 2); t0 += __shfl_xor(t0, 4);
            float t1 = e1;
            t1 += __shfl_xor(t1, 1); t1 += __shfl_xor(t1, 2); t1 += __shfl_xor(t1, 4);
            a0[r] = e0 * (1.0f / t0) + EPS_ATTN;
            a1[r] = e1 * (1.0f / t1) + EPS_ATTN;
            rs += a0[r] + a1[r];
        }
        if (last && c < 8) {
            float4 st0 = {a0[0] * ainv, a0[1] * ainv, a0[2] * ainv, a0[3] * ainv};
            float4 st1 = {a1[0] * ainv, a1[1] * ainv, a1[2] * ainv, a1[3] * ainv};
            float* ap = attn_out + ((size_t)bh * 8 + c) * 4096 + base + g * 4;
            *(float4*)ap = st0;
            *(float4*)(ap + 16) = st1;
        }
        bf16x8 pah, pal;
        float af[8] = {a0[0], a0[1], a0[2], a0[3], a1[0], a1[1], a1[2], a1[3]};
        #pragma unroll
        for (int j = 0; j < 8; ++j) {
            unsigned short hb = f2b(af[j]);
            pah[j] = (short)hb;
            pal[j] = (short)f2b(af[j] - b2f(hb));
        }
        accL = __builtin_amdgcn_mfma_f32_16x16x32_bf16(V0.v, pah, accL, 0, 0, 0);
        accL = __builtin_amdgcn_mfma_f32_16x16x32_bf16(V0.v, pal, accL, 0, 0, 0);
        accH = __builtin_amdgcn_mfma_f32_16x16x32_bf16(V1.v, pah, accH, 0, 0, 0);
        accH = __builtin_amdgcn_mfma_f32_16x16x32_bf16(V1.v, pal, accH, 0, 0, 0);
    }

    if (!last) {
        rs += __shfl_xor(rs, 16);
        rs += __shfl_xor(rs, 32);
        if (lane < 8) srs[w][lane] = rs;
    }
    if (c < 8) {
        float* up = &supd[w][c * 32 + g * 4];
        up[0]  = accL[0]; up[1]  = accL[1]; up[2]  = accL[2]; up[3]  = accL[3];
        up[16] = accH[0]; up[17] = accH[1]; up[18] = accH[2]; up[19] = accH[3];
    }
    __syncthreads();
    {
        float v = supd[0][t] + supd[1][t] + supd[2][t] + supd[3][t];
        upd_part[((size_t)bh * 4 + chunk) * 256 + t] = v;
    }
    if (!last && t < 8) {
        float v = srs[0][t] + srs[1][t] + srs[2][t] + srs[3][t];
        rowsum_part[((size_t)bh * 4 + chunk) * 8 + t] = v;
    }
}

// ========== slot-update stage kernels (col-split, LDS row-broadcast) ==========
// Stage A: O = U @ wo + bo; sums the 4 attn partials.
__global__ __launch_bounds__(256) void k_gA(
    const float* __restrict__ upd_part, const float* __restrict__ rowsum_part,
    const float* __restrict__ wo, const float* __restrict__ bo,
    float* __restrict__ O) {
    __shared__ float Ul[8][256];
    __shared__ float Pp[4][8][64];
    int t = threadIdx.x;
    int b = blockIdx.x >> 2, cc = blockIdx.x & 3;
    int colbase = cc * 64;
    {
        int r = t >> 5, d0 = (t & 31) * 8;
        int h = (t & 31) >> 2;      // d0 >> 5
        float rsum = 0.f;
        #pragma unroll
        for (int ch = 0; ch < 4; ++ch)
            rsum += rowsum_part[((size_t)(b * 8 + h) * 4 + ch) * 8 + r];
        float inv = 1.0f / fmaxf(rsum, 1e-12f);
        float u[8] = {0.f,0.f,0.f,0.f,0.f,0.f,0.f,0.f};
        #pragma unroll
        for (int ch = 0; ch < 4; ++ch) {
            const float* up = upd_part + ((size_t)(b * 8 + h) * 4 + ch) * 256 + r * 32 + (d0 & 31);
            float4 u0 = *(const float4*)up;
            float4 u1 = *(const float4*)(up + 4);
            u[0] += u0.x; u[1] += u0.y; u[2] += u0.z; u[3] += u0.w;
            u[4] += u1.x; u[5] += u1.y; u[6] += u1.z; u[7] += u1.w;
        }
        #pragma unroll
        for (int i = 0; i < 8; ++i) Ul[r][d0 + i] = u[i] * inv;
    }
    __syncthreads();
    int c = t & 63, kq = t >> 6;
    float acc[8] = {0.f,0.f,0.f,0.f,0.f,0.f,0.f,0.f};
    const float* wp = wo + (size_t)(kq * 64) * 256 + colbase + c;
    #pragma unroll 16
    for (int k = 0; k < 64; ++k) {
        float wv_ = wp[(size_t)k * 256];
        int kk = kq * 64 + k;
        #pragma unroll
        for (int r = 0; r < 8; ++r) acc[r] += Ul[r][kk] * wv_;
    }
    #pragma unroll
    for (int r = 0; r < 8; ++r) Pp[kq][r][c] = acc[r];
    __syncthreads();
    #pragma unroll
    for (int j = 0; j < 2; ++j) {
        int o = t * 2 + j;
        int r = o >> 6, c2 = o & 63;
        float v = Pp[0][r][c2] + Pp[1][r][c2] + Pp[2][r][c2] + Pp[3][r][c2] + bo[colbase + c2];
        O[(size_t)(b * 8 + r) * 256 + colbase + c2] = v;
    }
}

__global__ __launch_bounds__(256) void k_gB(
    const float* __restrict__ O, const float* __restrict__ slin,
    const float* __restrict__ wih, const float* __restrict__ bih,
    const float* __restrict__ whh, const float* __restrict__ bhh,
    float* __restrict__ gcomb, float* __restrict__ xn, float* __restrict__ hn) {
    __shared__ float Ol[8][256], Hl[8][256];
    __shared__ float Px[2][8][128], Ph[2][8][128];
    int t = threadIdx.x;
    int b = blockIdx.x / 6, cc = blockIdx.x % 6;
    int colbase = cc * 128;
    {
        int r = t >> 5, d0 = (t & 31) * 8;
        const float* op = O + (size_t)(b * 8 + r) * 256 + d0;
        const float* hp = slin + (size_t)(b * 8 + r) * 256 + d0;
        *(float4*)&Ol[r][d0]     = *(const float4*)op;
        *(float4*)&Ol[r][d0 + 4] = *(const float4*)(op + 4);
        *(float4*)&Hl[r][d0]     = *(const float4*)hp;
        *(float4*)&Hl[r][d0 + 4] = *(const float4*)(hp + 4);
    }
    __syncthreads();
    int c = t & 127, kh = t >> 7;
    float ax[8] = {0.f,0.f,0.f,0.f,0.f,0.f,0.f,0.f};
    float ah[8] = {0.f,0.f,0.f,0.f,0.f,0.f,0.f,0.f};
    const float* wxp = wih + (size_t)(kh * 128) * 768 + colbase + c;
    const float* whp = whh + (size_t)(kh * 128) * 768 + colbase + c;
    #pragma unroll 8
    for (int k = 0; k < 128; ++k) {
        float wx = wxp[(size_t)k * 768];
        float wh = whp[(size_t)k * 768];
        int kk = kh * 128 + k;
        #pragma unroll
        for (int r = 0; r < 8; ++r) { ax[r] += Ol[r][kk] * wx; ah[r] += Hl[r][kk] * wh; }
    }
    #pragma unroll
    for (int r = 0; r < 8; ++r) { Px[kh][r][c] = ax[r]; Ph[kh][r][c] = ah[r]; }
    __syncthreads();
    #pragma unroll
    for (int j = 0; j < 4; ++j) {
        int o = t * 4 + j;               // [0,1024)
        int r = o >> 7, c2 = o & 127;
        int cg = colbase + c2;
        int row = b * 8 + r;
        float vx = Px[0][r][c2] + Px[1][r][c2] + bih[cg];
        float vh = Ph[0][r][c2] + Ph[1][r][c2] + bhh[cg];
        if (cg < 512) {
            gcomb[(size_t)row * 512 + cg] = vx + vh;
        } else {
            xn[(size_t)row * 256 + cg - 512] = vx;
            hn[(size_t)row * 256 + cg - 512] = vh;
        }
    }
}

__global__ __launch_bounds__(256) void k_gC(
    const float* __restrict__ gcomb, const float* __restrict__ xn, const float* __restrict__ hn,
    const float* __restrict__ slin, const float* __restrict__ lnfw, const float* __restrict__ lnfb,
    float* __restrict__ slout, float* __restrict__ F) {
    __shared__ float red[8];
    int t = threadIdx.x, row = blockIdx.x;
    float a_r = gcomb[(size_t)row * 512 + t];
    float a_z = gcomb[(size_t)row * 512 + 256 + t];
    float xnv = xn[(size_t)row * 256 + t];
    float hnv = hn[(size_t)row * 256 + t];
    float hp  = slin[(size_t)row * 256 + t];
    float rg = 1.f / (1.f + expf(-a_r));
    float zg = 1.f / (1.f + expf(-a_z));
    float ng = tanhf(xnv + rg * hnv);
    float s1 = (1.f - zg) * ng + zg * hp;
    slout[(size_t)row * 256 + t] = s1;
    float s0 = s1, sq = s1 * s1;
    #pragma unroll
    for (int o = 1; o < 64; o <<= 1) { s0 += __shfl_xor(s0, o); sq += __shfl_xor(sq, o); }
    if ((t & 63) == 0) { red[t >> 6] = s0; red[4 + (t >> 6)] = sq; }
    __syncthreads();
    float ts0 = red[0] + red[1] + red[2] + red[3];
    float ts1 = red[4] + red[5] + red[6] + red[7];
    float mean = ts0 * (1.f / 256.f);
    float var  = ts1 * (1.f / 256.f) - mean * mean;
    float rstd = rsqrtf(var + LN_EPS);
    F[(size_t)row * 256 + t] = (s1 - mean) * rstd * lnfw[t] + lnfb[t];
}

__global__ __launch_bounds__(256) void k_gD(
    const float* __restrict__ F, const float* __restrict__ w1, const float* __restrict__ b1,
    float* __restrict__ H1) {
    __shared__ float Fl[8][256];
    __shared__ float Pp[4][8][64];
    int t = threadIdx.x;
    int b = blockIdx.x >> 2, cc = blockIdx.x & 3;
    int colbase = cc * 64;
    {
        int r = t >> 5, d0 = (t & 31) * 8;
        const float* fp = F + (size_t)(b * 8 + r) * 256 + d0;
        *(float4*)&Fl[r][d0]     = *(const float4*)fp;
        *(float4*)&Fl[r][d0 + 4] = *(const float4*)(fp + 4);
    }
    __syncthreads();
    int c = t & 63, kq = t >> 6;
    float acc[8] = {0.f,0.f,0.f,0.f,0.f,0.f,0.f,0.f};
    const float* wp = w1 + (size_t)(kq * 64) * 256 + colbase + c;
    #pragma unroll 16
    for (int k = 0; k < 64; ++k) {
        float wv_ = wp[(size_t)k * 256];
        int kk = kq * 64 + k;
        #pragma unroll
        for (int r = 0; r < 8; ++r) acc[r] += Fl[r][kk] * wv_;
    }
    #pragma unroll
    for (int r = 0; r < 8; ++r) Pp[kq][r][c] = acc[r];
    __syncthreads();
    #pragma unroll
    for (int j = 0; j < 2; ++j) {
        int o = t * 2 + j;
        int r = o >> 6, c2 = o & 63;
        float v = Pp[0][r][c2] + Pp[1][r][c2] + Pp[2][r][c2] + Pp[3][r][c2] + b1[colbase + c2];
        H1[(size_t)(b * 8 + r) * 256 + colbase + c2] = fmaxf(v, 0.f);
    }
}

__global__ __launch_bounds__(256) void k_gE(
    const float* __restrict__ H1, const float* __restrict__ w2, const float* __restrict__ b2,
    float* __restrict__ slout) {
    __shared__ float Hl[8][256];
    __shared__ float Pp[4][8][64];
    int t = threadIdx.x;
    int b = blockIdx.x >> 2, cc = blockIdx.x & 3;
    int colbase = cc * 64;
    {
        int r = t >> 5, d0 = (t & 31) * 8;
        const float* hp = H1 + (size_t)(b * 8 + r) * 256 + d0;
        *(float4*)&Hl[r][d0]     = *(const float4*)hp;
        *(float4*)&Hl[r][d0 + 4] = *(const float4*)(hp + 4);
    }
    __syncthreads();
    int c = t & 63, kq = t >> 6;
    float acc[8] = {0.f,0.f,0.f,0.f,0.f,0.f,0.f,0.f};
    const float* wp = w2 + (size_t)(kq * 64) * 256 + colbase + c;
    #pragma unroll 16
    for (int k = 0; k < 64; ++k) {
        float wv_ = wp[(size_t)k * 256];
        int kk = kq * 64 + k;
        #pragma unroll
        for (int r = 0; r < 8; ++r) acc[r] += Hl[r][kk] * wv_;
    }
    #pragma unroll
    for (int r = 0; r < 8; ++r) Pp[kq][r][c] = acc[r];
    __syncthreads();
    #pragma unroll
    for (int j = 0; j < 2; ++j) {
        int o = t * 2 + j;
        int r = o >> 6, c2 = o & 63;
        size_t idx = (size_t)(b * 8 + r) * 256 + colbase + c2;
        float v = Pp[0][r][c2] + Pp[1][r][c2] + Pp[2][r][c2] + Pp[3][r][c2] + b2[colbase + c2];
        slout[idx] = slout[idx] + v;
    }
}

extern "C" void kernel_launch(void* const* d_in, const int* in_sizes, int n_in,
                              void* d_out, int out_size, void* d_ws, size_t ws_size,
                              hipStream_t stream) {
    const float* inputs = (const float*)d_in[0];
    const float* noise  = (const float*)d_in[1];
    const float* sm     = (const float*)d_in[2];
    const float* slv    = (const float*)d_in[3];
    const float* wq     = (const float*)d_in[4];
    const float* bq     = (const float*)d_in[5];
    const float* wk     = (const float*)d_in[6];
    const float* bk     = (const float*)d_in[7];
    const float* wv     = (const float*)d_in[8];
    const float* bv     = (const float*)d_in[9];
    const float* wo     = (const float*)d_in[10];
    const float* bo     = (const float*)d_in[11];
    const float* wih    = (const float*)d_in[12];
    const float* bih    = (const float*)d_in[13];
    const float* whh    = (const float*)d_in[14];
    const float* bhh    = (const float*)d_in[15];
    const float* w1     = (const float*)d_in[16];
    const float* b1     = (const float*)d_in[17];
    const float* w2     = (const float*)d_in[18];
    const float* b2     = (const float*)d_in[19];
    const float* lniw   = (const float*)d_in[20];
    const float* lnib   = (const float*)d_in[21];
    const float* lnsw   = (const float*)d_in[22];
    const float* lnsb   = (const float*)d_in[23];
    const float* lnfw   = (const float*)d_in[24];
    const float* lnfb   = (const float*)d_in[25];

    char* ws = (char*)d_ws;
    unsigned short* Kb = (unsigned short*)ws;                         // 134,217,728  [bh][n][32]
    unsigned short* Vb = (unsigned short*)(ws + 134217728ull);        // 134,217,728  [bh][d][4096] (transposed)
    float* slotsA  = (float*)(ws + 268435456ull);                     // 524,288
    float* slotsB  = (float*)(ws + 268959744ull);                     // 524,288
    float* Rr      = (float*)(ws + 269484032ull);                     // 524,288  (qg / F)
    float* Pr      = (float*)(ws + 270008320ull);                     // 524,288  (W3 / O)
    float* Qr      = (float*)(ws + 270532608ull);                     // 2,097,152 (upd_part / gcomb|xn|hn / H1)
    float* rowsum_part = (float*)(ws + 272629760ull);                 // 65,536
    unsigned short* W3 = (unsigned short*)Pr;
    float* O_  = Pr;
    float* upd_part = Qr;                 // 512x4x256 (attn -> gA, dead by gB)
    float* gcomb = Qr;                    // 512x512
    float* xn = Qr + 262144;              // 512x256
    float* hn = Qr + 393216;              // 512x256
    float* H1 = Qr;                       // 512x256 (aliases gcomb, gB->gC dead by gD)
    float* qg = Rr;
    float* F_ = Rr;

    float* out_slots = (float*)d_out;            // [64,8,256]
    float* attn_out  = (float*)d_out + 131072;   // [64,8,8,4096]

    k_prep<<<512, 256, 0, stream>>>(wk, wv, W3);
    k_init<<<512, 256, 0, stream>>>(sm, slv, noise, slotsA);
    k_kv<<<4096, 256, 0, stream>>>(inputs, lniw, lnib, W3, bk, bv, Kb, Vb);
    for (int it = 0; it < 3; ++it) {
        int last = (it == 2);
        float* sl_in  = (it == 0) ? slotsA : ((it == 1) ? slotsB : slotsA);
        float* sl_out = (it == 0) ? slotsB : ((it == 1) ? slotsA : out_slots);
        k_q<<<512, 256, 0, stream>>>(sl_in, lnsw, lnsb, wq, bq, qg);
        if (last) k_pre<<<2048, 256, 0, stream>>>(Kb, qg, rowsum_part);
        k_attn<<<2048, 256, 0, stream>>>(Kb, Vb, qg, upd_part, rowsum_part, attn_out, last);
        k_gA<<<256, 256, 0, stream>>>(upd_part, rowsum_part, wo, bo, O_);
        k_gB<<<384, 256, 0, stream>>>(O_, sl_in, wih, bih, whh, bhh, gcomb, xn, hn);
        k_gC<<<512, 256, 0, stream>>>(gcomb, xn, hn, sl_in, lnfw, lnfb, sl_out, F_);
        k_gD<<<256, 256, 0, stream>>>(F_, w1, b1, H1);
        k_gE<<<256, 256, 0, stream>>>(H1, w2, b2, sl_out);
    }
}

// Round 6
// 1008.208 us; speedup vs baseline: 1.3964x; 1.0166x over previous
//
#include <hip/hip_runtime.h>
#include <stdint.h>

// ---------- helpers ----------
typedef __attribute__((ext_vector_type(8))) short bf16x8;
typedef __attribute__((ext_vector_type(4))) float f32x4;

__device__ __forceinline__ float b2f(unsigned short s) {
    unsigned int u = ((unsigned int)s) << 16;
    return __builtin_bit_cast(float, u);
}
__device__ __forceinline__ unsigned short f2b(float f) {
    unsigned int u = __builtin_bit_cast(unsigned int, f);
    u += 0x7FFFu + ((u >> 16) & 1u);   // RNE
    return (unsigned short)(u >> 16);
}

#define EPS_ATTN 1e-8f
#define LN_EPS 1e-5f
#define SCALE 0.0625f  // 256^-0.5

// ---------- prep: W3 in MFMA B-fragment order ----------
__global__ __launch_bounds__(256) void k_prep(const float* __restrict__ wk,
                                              const float* __restrict__ wv,
                                              unsigned short* __restrict__ W3) {
    int g = blockIdx.x * 256 + threadIdx.x;   // 131072
    int j = g & 7;
    int f = (g >> 3) & 1023;
    int stage = g >> 13;
    int p = f & 15, qq = (f >> 4) & 3, ntl = f >> 6;
    int kc = stage >> 1, half_ = stage & 1;
    int k = kc * 32 + qq * 8 + j;
    int n = half_ * 256 + ntl * 16 + p;
    float v = (n < 256) ? wk[k * 256 + n] : wv[k * 256 + (n - 256)];
    W3[g] = f2b(v);
}

// ---------- slot init ----------
__global__ __launch_bounds__(256) void k_init(const float* __restrict__ sm,
                                              const float* __restrict__ slv,
                                              const float* __restrict__ noise,
                                              float* __restrict__ slots) {
    int idx = blockIdx.x * 256 + threadIdx.x; // 131072
    int d = idx & 255;
    slots[idx] = sm[d] + expf(slv[d]) * noise[idx];
}

// ---------- fused LN(inputs) + K/V projection (unchanged from R5) ----------
__global__ __launch_bounds__(256, 2) void k_kv(
    const float* __restrict__ x, const float* __restrict__ lnw, const float* __restrict__ lnb,
    const unsigned short* __restrict__ W3, const float* __restrict__ bk, const float* __restrict__ bv,
    unsigned short* __restrict__ Kb, unsigned short* __restrict__ Vb) {
    __shared__ __align__(16) unsigned short sh[16384];  // 32KB: A frags, then repK, then repV
    __shared__ __align__(16) float bL[512];             // 2KB biases
    unsigned short* As = sh;
    int t = threadIdx.x;
    int w = t >> 6, lane = t & 63;
    int p = lane & 15, q = lane >> 4;

    if (t < 128) {
        float4 bb = (t < 64) ? ((const float4*)bk)[t] : ((const float4*)bv)[t - 64];
        *(float4*)&bL[t * 4] = bb;
    }

    float4 lw  = ((const float4*)lnw)[lane];
    float4 lbv = ((const float4*)lnb)[lane];
    float4 xv[16];
    const float* xbase = x + ((size_t)blockIdx.x * 64 + w * 16) * 256;
    #pragma unroll
    for (int i = 0; i < 16; ++i) xv[i] = ((const float4*)(xbase + i * 256))[lane];
    int kcw = lane >> 3, qw = (lane >> 1) & 3, j0 = (lane & 1) * 4;
    #pragma unroll
    for (int i = 0; i < 16; ++i) {
        float4 v = xv[i];
        float s0 = v.x + v.y + v.z + v.w;
        float s1 = v.x * v.x + v.y * v.y + v.z * v.z + v.w * v.w;
        #pragma unroll
        for (int o = 1; o < 64; o <<= 1) { s0 += __shfl_xor(s0, o); s1 += __shfl_xor(s1, o); }
        float mean = s0 * (1.0f / 256.0f);
        float var  = s1 * (1.0f / 256.0f) - mean * mean;
        float rstd = rsqrtf(var + LN_EPS);
        ushort4 pk;
        pk.x = f2b((v.x - mean) * rstd * lw.x + lbv.x);
        pk.y = f2b((v.y - mean) * rstd * lw.y + lbv.y);
        pk.z = f2b((v.z - mean) * rstd * lw.z + lbv.z);
        pk.w = f2b((v.w - mean) * rstd * lw.w + lbv.w);
        int pos = (qw * 16 + i) ^ kcw;
        *(ushort4*)&As[((w * 8 + kcw) * 64 + pos) * 8 + j0] = pk;
    }
    __syncthreads();

    f32x4 acc[4][8];
    f32x4 zero = {0.f, 0.f, 0.f, 0.f};
    #pragma unroll
    for (int rt = 0; rt < 4; ++rt)
        #pragma unroll
        for (int ct = 0; ct < 8; ++ct) acc[rt][ct] = zero;

    const unsigned short* WbL = W3 + lane * 8;
    #pragma unroll 2
    for (int kc = 0; kc < 8; ++kc) {
        bf16x8 af[4];
        #pragma unroll
        for (int rt = 0; rt < 4; ++rt)
            af[rt] = *(const bf16x8*)&As[((rt * 8 + kc) * 64 + ((q * 16 + p) ^ kc)) * 8];
        #pragma unroll
        for (int ct = 0; ct < 8; ++ct) {
            int half_ = ct >> 2;
            int ntl = w * 4 + (ct & 3);
            bf16x8 bf = *(const bf16x8*)(WbL + (size_t)kc * 16384 + half_ * 8192 + ntl * 512);
            #pragma unroll
            for (int rt = 0; rt < 4; ++rt)
                acc[rt][ct] = __builtin_amdgcn_mfma_f32_16x16x32_bf16(af[rt], bf, acc[rt][ct], 0, 0, 0);
        }
    }
    __syncthreads();   // As reads done; safe to overwrite

    unsigned short* rep = As;
    int b_  = blockIdx.x >> 6;
    int n0g = (blockIdx.x & 63) * 64;

    // ---- pass 1: K stage (ALL waves) ----
    #pragma unroll
    for (int ct = 0; ct < 4; ++ct) {
        int col = w * 64 + ct * 16 + p;
        float bias = bL[col];
        int hl = col >> 5, dh = col & 31;
        int dlo = dh & 7, dch = dh >> 3;
        int dchs = dch ^ q;
        #pragma unroll
        for (int rt = 0; rt < 4; ++rt) {
            #pragma unroll
            for (int r = 0; r < 4; ++r) {
                int nl = rt * 16 + q * 4 + r;
                rep[(hl * 64 + nl) * 32 + dchs * 8 + dlo] = f2b(acc[rt][ct][r] + bias);
            }
        }
    }
    __syncthreads();
    {
        int nl = t >> 2, dhc = t & 3;
        int swz = (nl >> 2) & 3;
        #pragma unroll
        for (int i = 0; i < 8; ++i) {
            uint4 vd = *(const uint4*)&rep[((i * 64 + nl) * 32) + ((dhc ^ swz) * 8)];
            *(uint4*)(Kb + (((size_t)b_ * 8 + i) * 4096 + n0g + nl) * 32 + dhc * 8) = vd;
        }
    }
    __syncthreads();

    // ---- pass 2: V stage (ALL waves), even-XOR chunk swizzle ----
    #pragma unroll
    for (int ct = 4; ct < 8; ++ct) {
        int vrow = w * 64 + (ct - 4) * 16 + p;
        float bias = bL[256 + vrow];
        #pragma unroll
        for (int rt = 0; rt < 4; ++rt) {
            int chunk = (rt * 4 + q) ^ (p & 14);
            ushort4 pk;
            pk.x = f2b(acc[rt][ct][0] + bias);
            pk.y = f2b(acc[rt][ct][1] + bias);
            pk.z = f2b(acc[rt][ct][2] + bias);
            pk.w = f2b(acc[rt][ct][3] + bias);
            *(ushort4*)&rep[vrow * 64 + chunk * 4] = pk;
        }
    }
    __syncthreads();
    #pragma unroll
    for (int i = 0; i < 8; ++i) {
        int vrow = i * 32 + (t >> 3);
        int c16 = t & 7;
        uint4 vd = *(const uint4*)&rep[vrow * 64 + ((2 * c16) ^ (vrow & 14)) * 4];
        *(uint4*)(Vb + ((size_t)(b_ * 8 + (vrow >> 5)) * 32 + (vrow & 31)) * 4096 + n0g + c16 * 8) = vd;
    }
}

// ---------- q projection (iteration 0 only) ----------
__global__ __launch_bounds__(256) void k_q(
    const float* __restrict__ slots, const float* __restrict__ lnw, const float* __restrict__ lnb,
    const float* __restrict__ wq, const float* __restrict__ bq, float* __restrict__ qg) {
    __shared__ float sln[256];
    __shared__ float red[8];
    int t = threadIdx.x;
    int row = blockIdx.x;
    float v = slots[(size_t)row * 256 + t];
    float s0 = v, s1 = v * v;
    #pragma unroll
    for (int off = 1; off < 64; off <<= 1) { s0 += __shfl_xor(s0, off); s1 += __shfl_xor(s1, off); }
    if ((t & 63) == 0) { red[t >> 6] = s0; red[4 + (t >> 6)] = s1; }
    __syncthreads();
    float ts0 = red[0] + red[1] + red[2] + red[3];
    float ts1 = red[4] + red[5] + red[6] + red[7];
    float mean = ts0 * (1.f / 256.f);
    float var  = ts1 * (1.f / 256.f) - mean * mean;
    float rstd = rsqrtf(var + LN_EPS);
    sln[t] = (v - mean) * rstd * lnw[t] + lnb[t];
    __syncthreads();
    float acc = bq[t];
    #pragma unroll 4
    for (int k = 0; k < 256; ++k) acc += sln[k] * wq[k * 256 + t];
    int b = row >> 3, sl = row & 7;
    qg[(size_t)b * 2048 + (t >> 5) * 256 + sl * 32 + (t & 31)] = acc;
}

// ---------- rowsum pre-pass (last iteration only) ----------
__global__ __launch_bounds__(256) void k_pre(
    const unsigned short* __restrict__ Kg, const float* __restrict__ qg,
    float* __restrict__ rowsum_part) {
    __shared__ float srs[4][8];
    int t = threadIdx.x;
    int w = t >> 6, lane = t & 63;
    int c = lane & 15, g = lane >> 4;
    int bh = blockIdx.x >> 2;
    int chunk = blockIdx.x & 3;
    const unsigned short* Kbh = Kg + (size_t)bh * 4096 * 32;

    bf16x8 qhi = {0,0,0,0,0,0,0,0};
    bf16x8 qlo = {0,0,0,0,0,0,0,0};
    if (c < 8) {
        const float* qp = qg + (size_t)bh * 256 + c * 32 + g * 8;
        #pragma unroll
        for (int j = 0; j < 8; ++j) {
            float qv = qp[j];
            unsigned short hb = f2b(qv);
            qhi[j] = (short)hb;
            qlo[j] = (short)f2b(qv - b2f(hb));
        }
    }

    f32x4 zero = {0.f, 0.f, 0.f, 0.f};
    float rs = 0.f;
    int nb0 = chunk * 1024 + w * 256;

    #pragma unroll 2
    for (int pr = 0; pr < 8; ++pr) {
        int base = nb0 + pr * 32;
        bf16x8 k0 = *(const bf16x8*)(Kbh + (size_t)(base + c) * 32 + g * 8);
        bf16x8 k1 = *(const bf16x8*)(Kbh + (size_t)(base + 16 + c) * 32 + g * 8);
        f32x4 s0 = __builtin_amdgcn_mfma_f32_16x16x32_bf16(k0, qhi, zero, 0, 0, 0);
        s0 = __builtin_amdgcn_mfma_f32_16x16x32_bf16(k0, qlo, s0, 0, 0, 0);
        f32x4 s1 = __builtin_amdgcn_mfma_f32_16x16x32_bf16(k1, qhi, zero, 0, 0, 0);
        s1 = __builtin_amdgcn_mfma_f32_16x16x32_bf16(k1, qlo, s1, 0, 0, 0);
        float d0[4], d1[4];
        #pragma unroll
        for (int r = 0; r < 4; ++r) { d0[r] = s0[r] * SCALE; d1[r] = s1[r] * SCALE; }
        float m = fmaxf(fmaxf(fmaxf(d0[0], d0[1]), fmaxf(d0[2], d0[3])),
                        fmaxf(fmaxf(d1[0], d1[1]), fmaxf(d1[2], d1[3])));
        m = fmaxf(m, __shfl_xor(m, 1));
        m = fmaxf(m, __shfl_xor(m, 2));
        m = fmaxf(m, __shfl_xor(m, 4));
        m = fmaxf(m, __shfl_xor(m, 8));
        #pragma unroll
        for (int r = 0; r < 4; ++r) {
            float e0 = __expf(d0[r] - m);
            float e1 = __expf(d1[r] - m);
            float t0 = e0;
            t0 += __shfl_xor(t0, 1); t0 += __shfl_xor(t0, 2); t0 += __shfl_xor(t0, 4);
            float t1 = e1;
            t1 += __shfl_xor(t1, 1); t1 += __shfl_xor(t1, 2); t1 += __shfl_xor(t1, 4);
            rs += (e0 * (1.0f / t0) + EPS_ATTN) + (e1 * (1.0f / t1) + EPS_ATTN);
        }
    }
    rs += __shfl_xor(rs, 16);
    rs += __shfl_xor(rs, 32);
    if (lane < 8) srs[w][lane] = rs;
    __syncthreads();
    if (t < 8) {
        rowsum_part[((size_t)bh * 4 + chunk) * 8 + t] =
            srs[0][t] + srs[1][t] + srs[2][t] + srs[3][t];
    }
}

// ---------- attention sweep: MFMA QK^T (swapped) + MFMA PV ----------
__global__ __launch_bounds__(256) void k_attn(
    const unsigned short* __restrict__ Kg, const unsigned short* __restrict__ VTg,
    const float* __restrict__ qg, float* __restrict__ upd_part, float* __restrict__ rowsum_part,
    float* __restrict__ attn_out, int last) {
    __shared__ float supd[4][256];
    __shared__ float srs[4][8];
    int t = threadIdx.x;
    int w = t >> 6, lane = t & 63;
    int c = lane & 15;
    int g = lane >> 4;

    int bh = blockIdx.x >> 2;
    int chunk = blockIdx.x & 3;
    const unsigned short* Kbh = Kg  + (size_t)bh * 4096 * 32;
    const unsigned short* Vbh = VTg + (size_t)bh * 32 * 4096;

    bf16x8 qhi = {0,0,0,0,0,0,0,0};
    bf16x8 qlo = {0,0,0,0,0,0,0,0};
    if (c < 8) {
        const float* qp = qg + (size_t)bh * 256 + c * 32 + g * 8;
        #pragma unroll
        for (int j = 0; j < 8; ++j) {
            float qv = qp[j];
            unsigned short hb = f2b(qv);
            qhi[j] = (short)hb;
            qlo[j] = (short)f2b(qv - b2f(hb));
        }
    }
    float ainv = 0.f;
    if (last && c < 8) {
        float rsum = 0.f;
        #pragma unroll
        for (int ch = 0; ch < 4; ++ch) rsum += rowsum_part[((size_t)bh * 4 + ch) * 8 + c];
        ainv = 1.0f / fmaxf(rsum, 1e-12f);
    }

    f32x4 zero = {0.f, 0.f, 0.f, 0.f};
    f32x4 accL = zero, accH = zero;
    float rs = 0.f;
    int nb0 = chunk * 1024 + w * 256;

    #pragma unroll 2
    for (int pr = 0; pr < 8; ++pr) {
        int base = nb0 + pr * 32;
        bf16x8 k0 = *(const bf16x8*)(Kbh + (size_t)(base + c) * 32 + g * 8);
        bf16x8 k1 = *(const bf16x8*)(Kbh + (size_t)(base + 16 + c) * 32 + g * 8);
        const unsigned short* vlo = Vbh + (size_t)c * 4096 + base + g * 4;
        const unsigned short* vhi = Vbh + (size_t)(c + 16) * 4096 + base + g * 4;
        union { ushort4 h[2]; bf16x8 v; } V0, V1;
        V0.h[0] = *(const ushort4*)vlo;
        V0.h[1] = *(const ushort4*)(vlo + 16);
        V1.h[0] = *(const ushort4*)vhi;
        V1.h[1] = *(const ushort4*)(vhi + 16);

        f32x4 s0 = __builtin_amdgcn_mfma_f32_16x16x32_bf16(k0, qhi, zero, 0, 0, 0);
        s0 = __builtin_amdgcn_mfma_f32_16x16x32_bf16(k0, qlo, s0, 0, 0, 0);
        f32x4 s1 = __builtin_amdgcn_mfma_f32_16x16x32_bf16(k1, qhi, zero, 0, 0, 0);
        s1 = __builtin_amdgcn_mfma_f32_16x16x32_bf16(k1, qlo, s1, 0, 0, 0);

        float d0[4], d1[4];
        #pragma unroll
        for (int r = 0; r < 4; ++r) { d0[r] = s0[r] * SCALE; d1[r] = s1[r] * SCALE; }
        float m = fmaxf(fmaxf(fmaxf(d0[0], d0[1]), fmaxf(d0[2], d0[3])),
                        fmaxf(fmaxf(d1[0], d1[1]), fmaxf(d1[2], d1[3])));
        m = fmaxf(m, __shfl_xor(m, 1));
        m = fmaxf(m, __shfl_xor(m, 2));
        m = fmaxf(m, __shfl_xor(m, 4));
        m = fmaxf(m, __shfl_xor(m, 8));
        float a0[4], a1[4];
        #pragma unroll
        for (int r = 0; r < 4; ++r) {
            float e0 = __expf(d0[r] - m);
            float e1 = __expf(d1[r] - m);
            float t0 = e0;
            t0 += __shfl_xor(t0, 1); t0 += __shfl_xor(t0, 2); t0 += __shfl_xor(t0, 4);
            float t1 = e1;
            t1 += __shfl_xor(t1, 1); t1 += __shfl_xor(t1, 2); t1 += __shfl_xor(t1, 4);
            a0[r] = e0 * (1.0f / t0) + EPS_ATTN;
            a1[r] = e1 * (1.0f / t1) + EPS_ATTN;
            rs += a0[r] + a1[r];
        }
        if (last && c < 8) {
            float4 st0 = {a0[0] * ainv, a0[1] * ainv, a0[2] * ainv, a0[3] * ainv};
            float4 st1 = {a1[0] * ainv, a1[1] * ainv, a1[2] * ainv, a1[3] * ainv};
            float* ap = attn_out + ((size_t)bh * 8 + c) * 4096 + base + g * 4;
            *(float4*)ap = st0;
            *(float4*)(ap + 16) = st1;
        }
        bf16x8 pah, pal;
        float af[8] = {a0[0], a0[1], a0[2], a0[3], a1[0], a1[1], a1[2], a1[3]};
        #pragma unroll
        for (int j = 0; j < 8; ++j) {
            unsigned short hb = f2b(af[j]);
            pah[j] = (short)hb;
            pal[j] = (short)f2b(af[j] - b2f(hb));
        }
        accL = __builtin_amdgcn_mfma_f32_16x16x32_bf16(V0.v, pah, accL, 0, 0, 0);
        accL = __builtin_amdgcn_mfma_f32_16x16x32_bf16(V0.v, pal, accL, 0, 0, 0);
        accH = __builtin_amdgcn_mfma_f32_16x16x32_bf16(V1.v, pah, accH, 0, 0, 0);
        accH = __builtin_amdgcn_mfma_f32_16x16x32_bf16(V1.v, pal, accH, 0, 0, 0);
    }

    if (!last) {
        rs += __shfl_xor(rs, 16);
        rs += __shfl_xor(rs, 32);
        if (lane < 8) srs[w][lane] = rs;
    }
    if (c < 8) {
        float* up = &supd[w][c * 32 + g * 4];
        up[0]  = accL[0]; up[1]  = accL[1]; up[2]  = accL[2]; up[3]  = accL[3];
        up[16] = accH[0]; up[17] = accH[1]; up[18] = accH[2]; up[19] = accH[3];
    }
    __syncthreads();
    {
        float v = supd[0][t] + supd[1][t] + supd[2][t] + supd[3][t];
        upd_part[((size_t)bh * 4 + chunk) * 256 + t] = v;
    }
    if (!last && t < 8) {
        float v = srs[0][t] + srs[1][t] + srs[2][t] + srs[3][t];
        rowsum_part[((size_t)bh * 4 + chunk) * 8 + t] = v;
    }
}

// ---------- FUSED slot update: U->O->GRU->LN->FFN->(+res)->[LN->q] ----------
// grid 256 = b(64) x slot-pair(4); 256 threads; thread t owns output column t for
// TWO slot rows. All intermediates in LDS/registers; weights L2-broadcast.
__global__ __launch_bounds__(256) void k_upd(
    const float* __restrict__ upd_part, const float* __restrict__ rowsum_part,
    const float* __restrict__ slin,
    const float* __restrict__ wo, const float* __restrict__ bo,
    const float* __restrict__ wih, const float* __restrict__ bih,
    const float* __restrict__ whh, const float* __restrict__ bhh,
    const float* __restrict__ lnfw, const float* __restrict__ lnfb,
    const float* __restrict__ w1, const float* __restrict__ b1,
    const float* __restrict__ w2, const float* __restrict__ b2,
    const float* __restrict__ lnsw, const float* __restrict__ lnsb,
    const float* __restrict__ wq, const float* __restrict__ bq,
    float* __restrict__ slout, float* __restrict__ qg, int do_q) {
    __shared__ float Ul[2][256];
    __shared__ float Ol[2][256];
    __shared__ float Hl[2][256];
    __shared__ float Fl[2][256];
    __shared__ float Xl[2][256];     // H1, then sln
    __shared__ float red4[4][4];
    int t = threadIdx.x;
    int lane = t & 63, wvi = t >> 6;
    int b = blockIdx.x >> 2, sp = blockIdx.x & 3;
    int row0 = b * 8 + sp * 2;
    int h = t >> 5, dd = t & 31;

    // ---- U = (sum of 4 attn partials) / rowsum ; Hp = slots_prev ----
    #pragma unroll
    for (int r = 0; r < 2; ++r) {
        int sl = sp * 2 + r;
        float rsum = 0.f, u = 0.f;
        #pragma unroll
        for (int ch = 0; ch < 4; ++ch) {
            rsum += rowsum_part[((size_t)(b * 8 + h) * 4 + ch) * 8 + sl];
            u    += upd_part[((size_t)(b * 8 + h) * 4 + ch) * 256 + sl * 32 + dd];
        }
        Ul[r][t] = u / fmaxf(rsum, 1e-12f);
        Hl[r][t] = slin[(size_t)(row0 + r) * 256 + t];
    }
    __syncthreads();

    // ---- O = U @ wo + bo ----
    {
        float a0 = 0.f, a1 = 0.f;
        #pragma unroll 8
        for (int k = 0; k < 256; ++k) {
            float w_ = wo[k * 256 + t];
            a0 += Ul[0][k] * w_;
            a1 += Ul[1][k] * w_;
        }
        float bb = bo[t];
        Ol[0][t] = a0 + bb;
        Ol[1][t] = a1 + bb;
    }
    __syncthreads();

    // ---- GRU gates: xg = O@wih, hg = Hp@whh (cols t, 256+t, 512+t) ----
    float xg00 = 0.f, xg01 = 0.f, xg02 = 0.f, xg10 = 0.f, xg11 = 0.f, xg12 = 0.f;
    float hg00 = 0.f, hg01 = 0.f, hg02 = 0.f, hg10 = 0.f, hg11 = 0.f, hg12 = 0.f;
    #pragma unroll 4
    for (int k = 0; k < 256; ++k) {
        float o0 = Ol[0][k], o1 = Ol[1][k];
        float p0 = Hl[0][k], p1 = Hl[1][k];
        const float* wx = wih + (size_t)k * 768 + t;
        const float* wh = whh + (size_t)k * 768 + t;
        float wx0 = wx[0], wx1 = wx[256], wx2 = wx[512];
        float wh0 = wh[0], wh1 = wh[256], wh2 = wh[512];
        xg00 += o0 * wx0; xg01 += o0 * wx1; xg02 += o0 * wx2;
        xg10 += o1 * wx0; xg11 += o1 * wx1; xg12 += o1 * wx2;
        hg00 += p0 * wh0; hg01 += p0 * wh1; hg02 += p0 * wh2;
        hg10 += p1 * wh0; hg11 += p1 * wh1; hg12 += p1 * wh2;
    }
    float bi0 = bih[t], bi1 = bih[256 + t], bi2 = bih[512 + t];
    float bh0 = bhh[t], bh1 = bhh[256 + t], bh2 = bhh[512 + t];
    float s1v0, s1v1;
    {
        float rg = 1.f / (1.f + expf(-((xg00 + bi0) + (hg00 + bh0))));
        float zg = 1.f / (1.f + expf(-((xg01 + bi1) + (hg01 + bh1))));
        float ng = tanhf((xg02 + bi2) + rg * (hg02 + bh2));
        s1v0 = (1.f - zg) * ng + zg * Hl[0][t];
        rg = 1.f / (1.f + expf(-((xg10 + bi0) + (hg10 + bh0))));
        zg = 1.f / (1.f + expf(-((xg11 + bi1) + (hg11 + bh1))));
        ng = tanhf((xg12 + bi2) + rg * (hg12 + bh2));
        s1v1 = (1.f - zg) * ng + zg * Hl[1][t];
    }

    // ---- LN(s1) -> F ----
    {
        float a = s1v0, sa = s1v0 * s1v0, c = s1v1, sc = s1v1 * s1v1;
        #pragma unroll
        for (int o = 1; o < 64; o <<= 1) {
            a += __shfl_xor(a, o); sa += __shfl_xor(sa, o);
            c += __shfl_xor(c, o); sc += __shfl_xor(sc, o);
        }
        if (lane == 0) { red4[wvi][0] = a; red4[wvi][1] = sa; red4[wvi][2] = c; red4[wvi][3] = sc; }
        __syncthreads();
        float t0 = red4[0][0] + red4[1][0] + red4[2][0] + red4[3][0];
        float t1 = red4[0][1] + red4[1][1] + red4[2][1] + red4[3][1];
        float t2 = red4[0][2] + red4[1][2] + red4[2][2] + red4[3][2];
        float t3 = red4[0][3] + red4[1][3] + red4[2][3] + red4[3][3];
        float m0 = t0 * (1.f / 256.f), v0 = t1 * (1.f / 256.f) - m0 * m0;
        float m1 = t2 * (1.f / 256.f), v1 = t3 * (1.f / 256.f) - m1 * m1;
        float r0 = rsqrtf(v0 + LN_EPS), r1 = rsqrtf(v1 + LN_EPS);
        float lw = lnfw[t], lb = lnfb[t];
        Fl[0][t] = (s1v0 - m0) * r0 * lw + lb;
        Fl[1][t] = (s1v1 - m1) * r1 * lw + lb;
    }
    __syncthreads();

    // ---- H1 = relu(F @ w1 + b1) ----
    {
        float a0 = 0.f, a1 = 0.f;
        #pragma unroll 8
        for (int k = 0; k < 256; ++k) {
            float w_ = w1[k * 256 + t];
            a0 += Fl[0][k] * w_;
            a1 += Fl[1][k] * w_;
        }
        float bb = b1[t];
        Xl[0][t] = fmaxf(a0 + bb, 0.f);
        Xl[1][t] = fmaxf(a1 + bb, 0.f);
    }
    __syncthreads();

    // ---- out = s1 + H1 @ w2 + b2 ----
    float out0, out1;
    {
        float a0 = 0.f, a1 = 0.f;
        #pragma unroll 8
        for (int k = 0; k < 256; ++k) {
            float w_ = w2[k * 256 + t];
            a0 += Xl[0][k] * w_;
            a1 += Xl[1][k] * w_;
        }
        float bb = b2[t];
        out0 = s1v0 + a0 + bb;
        out1 = s1v1 + a1 + bb;
        slout[(size_t)(row0 + 0) * 256 + t] = out0;
        slout[(size_t)(row0 + 1) * 256 + t] = out1;
    }

    if (!do_q) return;

    // ---- q for next iteration: LN(out) @ wq + bq ----
    __syncthreads();    // all Xl/red4 readers done
    {
        float a = out0, sa = out0 * out0, c = out1, sc = out1 * out1;
        #pragma unroll
        for (int o = 1; o < 64; o <<= 1) {
            a += __shfl_xor(a, o); sa += __shfl_xor(sa, o);
            c += __shfl_xor(c, o); sc += __shfl_xor(sc, o);
        }
        if (lane == 0) { red4[wvi][0] = a; red4[wvi][1] = sa; red4[wvi][2] = c; red4[wvi][3] = sc; }
        __syncthreads();
        float t0 = red4[0][0] + red4[1][0] + red4[2][0] + red4[3][0];
        float t1 = red4[0][1] + red4[1][1] + red4[2][1] + red4[3][1];
        float t2 = red4[0][2] + red4[1][2] + red4[2][2] + red4[3][2];
        float t3 = red4[0][3] + red4[1][3] + red4[2][3] + red4[3][3];
        float m0 = t0 * (1.f / 256.f), v0 = t1 * (1.f / 256.f) - m0 * m0;
        float m1 = t2 * (1.f / 256.f), v1 = t3 * (1.f / 256.f) - m1 * m1;
        float r0 = rsqrtf(v0 + LN_EPS), r1 = rsqrtf(v1 + LN_EPS);
        float lw = lnsw[t], lb = lnsb[t];
        Xl[0][t] = (out0 - m0) * r0 * lw + lb;
        Xl[1][t] = (out1 - m1) * r1 * lw + lb;
    }
    __syncthreads();
    {
        float a0 = 0.f, a1 = 0.f;
        #pragma unroll 8
        for (int k = 0; k < 256; ++k) {
            float w_ = wq[k * 256 + t];
            a0 += Xl[0][k] * w_;
            a1 += Xl[1][k] * w_;
        }
        float bb = bq[t];
        int sl0 = sp * 2;
        int d5 = t >> 5, d31 = t & 31;
        qg[(size_t)b * 2048 + d5 * 256 + sl0 * 32 + d31] = a0 + bb;
        qg[(size_t)b * 2048 + d5 * 256 + (sl0 + 1) * 32 + d31] = a1 + bb;
    }
}

extern "C" void kernel_launch(void* const* d_in, const int* in_sizes, int n_in,
                              void* d_out, int out_size, void* d_ws, size_t ws_size,
                              hipStream_t stream) {
    const float* inputs = (const float*)d_in[0];
    const float* noise  = (const float*)d_in[1];
    const float* sm     = (const float*)d_in[2];
    const float* slv    = (const float*)d_in[3];
    const float* wq     = (const float*)d_in[4];
    const float* bq     = (const float*)d_in[5];
    const float* wk     = (const float*)d_in[6];
    const float* bk     = (const float*)d_in[7];
    const float* wv     = (const float*)d_in[8];
    const float* bv     = (const float*)d_in[9];
    const float* wo     = (const float*)d_in[10];
    const float* bo     = (const float*)d_in[11];
    const float* wih    = (const float*)d_in[12];
    const float* bih    = (const float*)d_in[13];
    const float* whh    = (const float*)d_in[14];
    const float* bhh    = (const float*)d_in[15];
    const float* w1     = (const float*)d_in[16];
    const float* b1     = (const float*)d_in[17];
    const float* w2     = (const float*)d_in[18];
    const float* b2     = (const float*)d_in[19];
    const float* lniw   = (const float*)d_in[20];
    const float* lnib   = (const float*)d_in[21];
    const float* lnsw   = (const float*)d_in[22];
    const float* lnsb   = (const float*)d_in[23];
    const float* lnfw   = (const float*)d_in[24];
    const float* lnfb   = (const float*)d_in[25];

    char* ws = (char*)d_ws;
    unsigned short* Kb = (unsigned short*)ws;                         // 134,217,728  [bh][n][32]
    unsigned short* Vb = (unsigned short*)(ws + 134217728ull);        // 134,217,728  [bh][d][4096] (transposed)
    float* slotsA  = (float*)(ws + 268435456ull);                     // 524,288
    float* slotsB  = (float*)(ws + 268959744ull);                     // 524,288
    float* Rr      = (float*)(ws + 269484032ull);                     // 524,288  (qg)
    float* Pr      = (float*)(ws + 270008320ull);                     // 524,288  (W3)
    float* Qr      = (float*)(ws + 270532608ull);                     // 2,097,152 (upd_part)
    float* rowsum_part = (float*)(ws + 272629760ull);                 // 65,536
    unsigned short* W3 = (unsigned short*)Pr;
    float* upd_part = Qr;
    float* qg = Rr;

    float* out_slots = (float*)d_out;            // [64,8,256]
    float* attn_out  = (float*)d_out + 131072;   // [64,8,8,4096]

    k_prep<<<512, 256, 0, stream>>>(wk, wv, W3);
    k_init<<<512, 256, 0, stream>>>(sm, slv, noise, slotsA);
    k_kv<<<4096, 256, 0, stream>>>(inputs, lniw, lnib, W3, bk, bv, Kb, Vb);
    k_q<<<512, 256, 0, stream>>>(slotsA, lnsw, lnsb, wq, bq, qg);
    for (int it = 0; it < 3; ++it) {
        int last = (it == 2);
        float* sl_in  = (it == 0) ? slotsA : ((it == 1) ? slotsB : slotsA);
        float* sl_out = (it == 0) ? slotsB : ((it == 1) ? slotsA : out_slots);
        if (last) k_pre<<<2048, 256, 0, stream>>>(Kb, qg, rowsum_part);
        k_attn<<<2048, 256, 0, stream>>>(Kb, Vb, qg, upd_part, rowsum_part, attn_out, last);
        k_upd<<<256, 256, 0, stream>>>(upd_part, rowsum_part, sl_in,
                                       wo, bo, wih, bih, whh, bhh, lnfw, lnfb,
                                       w1, b1, w2, b2, lnsw, lnsb, wq, bq,
                                       sl_out, qg, last ? 0 : 1);
    }
}